// Round 5
// baseline (423.273 us; speedup 1.0000x reference)
//
#include <hip/hip_runtime.h>

#define NN 8192
#define EE 131072
#define HH 128
#define NEGV -1.0e30f
#define SEG 256
#define NSEG (NN / SEG)   // 32

typedef __attribute__((ext_vector_type(8))) short bf16x8;
typedef __attribute__((ext_vector_type(4))) float f32x4;

__device__ __forceinline__ unsigned short f2bf(float f) {
    unsigned int u = __float_as_uint(f);
    unsigned int r = u + 0x7fffu + ((u >> 16) & 1u);
    return (unsigned short)(r >> 16);
}
__device__ __forceinline__ float bf2f(unsigned short b) {
    return __uint_as_float((unsigned int)b << 16);
}

// ---------------- degree (int) ----------------

__global__ __launch_bounds__(256) void k_deg(const int* __restrict__ dst, int* __restrict__ degi) {
    int t = blockIdx.x * 256 + threadIdx.x;
    if (t < EE) atomicAdd(&degi[dst[t]], 1);
}

__global__ __launch_bounds__(256) void k_rsq(const int* __restrict__ degi, float* __restrict__ dinv,
                                             float* __restrict__ rsq) {
    int t = blockIdx.x * 256 + threadIdx.x;
    if (t < NN) {
        double d = (double)(degi[t] + 1);   // +1 self loop
        dinv[t] = (float)(1.0 / d);
        rsq[t] = (float)(1.0 / sqrt(d));
    }
}

// exclusive scan of degi[NN] -> rowptr[NN+1]; single block of 1024, 8 elems/thread
__global__ __launch_bounds__(1024) void k_scan(const int* __restrict__ degi, int* __restrict__ rowptr) {
    __shared__ int ls[1024];
    int tid = threadIdx.x;
    int base = tid * 8;
    int loc[8]; int s = 0;
#pragma unroll
    for (int i = 0; i < 8; i++) { loc[i] = s; s += degi[base + i]; }
    ls[tid] = s; __syncthreads();
    int tot = s;
    for (int d = 1; d < 1024; d <<= 1) {
        int v = (tid >= d) ? ls[tid - d] : 0;
        __syncthreads();
        ls[tid] += v;
        __syncthreads();
    }
    int pre = ls[tid] - tot;
#pragma unroll
    for (int i = 0; i < 8; i++) rowptr[base + i] = pre + loc[i];
    if (tid == 1023) rowptr[NN] = pre + tot;
}

__global__ __launch_bounds__(256) void k_fill(const int* __restrict__ src, const int* __restrict__ dst,
                                              const int* __restrict__ rowptr, int* __restrict__ cursor,
                                              int* __restrict__ ecsr) {
    int t = blockIdx.x * 256 + threadIdx.x;
    if (t < EE) {
        int d = dst[t];
        int pos = atomicAdd(&cursor[d], 1);
        ecsr[rowptr[d] + pos] = src[t];
    }
}

// ---------------- GCN: xw for conv1, gather-aggregate (fused bias+relu) ----------------

__global__ __launch_bounds__(256) void k_xw1(const float* __restrict__ x, const float* __restrict__ w,
                                             float* __restrict__ out) {
    int t = blockIdx.x * 256 + threadIdx.x;   // N*H threads
    int i = t >> 7, j = t & 127;
    out[t] = x[i * 2] * w[j * 2] + x[i * 2 + 1] * w[j * 2 + 1];
}

__global__ __launch_bounds__(256) void k_gather(const int* __restrict__ rowptr, const int* __restrict__ ecsr,
                                                const float* __restrict__ rsq, const float* __restrict__ dinv,
                                                const float* __restrict__ xw, const float* __restrict__ bias,
                                                float* __restrict__ out) {
    int g = blockIdx.x * 256 + threadIdx.x;
    int d = g >> 6, lane = g & 63;
    if (d >= NN) return;
    int s0 = rowptr[d], s1 = rowptr[d + 1];
    float rd = rsq[d];
    float a0 = 0.f, a1 = 0.f;
    for (int sl = s0; sl < s1; sl++) {
        int s = ecsr[sl];                       // wave-uniform scalar load
        float f = rsq[s] * rd;
        a0 = fmaf(f, xw[s * HH + lane], a0);    // coalesced 256B row segment
        a1 = fmaf(f, xw[s * HH + 64 + lane], a1);
    }
    float di = dinv[d];
    a0 = fmaf(xw[d * HH + lane], di, a0) + bias[lane];
    a1 = fmaf(xw[d * HH + 64 + lane], di, a1) + bias[64 + lane];
    out[d * HH + lane] = fmaxf(a0, 0.f);
    out[d * HH + 64 + lane] = fmaxf(a1, 0.f);
}

// ---------------- weight prep: transposes + folded-z biases ----------------
// T holds 7 transposed 128x128 mats: 0 conv2, 1 np1(h-part), 2 np2, 3 src, 4 tgt, 5 inv1(h_u), 6 inv1(h_v)

__global__ __launch_bounds__(256) void k_prep(const float* __restrict__ conv2_w, const float* __restrict__ np1_w,
                                              const float* __restrict__ np2_w, const float* __restrict__ src_w,
                                              const float* __restrict__ tgt_w, const float* __restrict__ inv1_w,
                                              const float* __restrict__ np1_b, const float* __restrict__ inv1_b,
                                              const float* __restrict__ z, float* __restrict__ T,
                                              float* __restrict__ c1, float* __restrict__ cz) {
    int y = blockIdx.y;
    if (y < 7) {
        int t = blockIdx.x * 256 + threadIdx.x;   // 16384 per matrix
        int j = t >> 7, k = t & 127;
        const float* W; int stride, off;
        switch (y) {
            case 0:  W = conv2_w; stride = 128; off = 0;   break;
            case 1:  W = np1_w;   stride = 256; off = 0;   break;
            case 2:  W = np2_w;   stride = 128; off = 0;   break;
            case 3:  W = src_w;   stride = 128; off = 0;   break;
            case 4:  W = tgt_w;   stride = 128; off = 0;   break;
            case 5:  W = inv1_w;  stride = 384; off = 0;   break;
            default: W = inv1_w;  stride = 384; off = 128; break;
        }
        T[y * 16384 + k * 128 + j] = W[j * stride + off + k];
    } else if (blockIdx.x == 0) {
        int tid = threadIdx.x;
        if (tid < 128) {
            float s = np1_b[tid];
            for (int k = 0; k < 128; k++) s += z[k] * np1_w[tid * 256 + 128 + k];
            c1[tid] = s;
        } else {
            int j = tid - 128;
            float s = inv1_b[j];
            for (int k = 0; k < 128; k++) s += z[k] * inv1_w[j * 384 + 256 + k];
            cz[j] = s;
        }
    }
}

// ---------------- generic [8192x128] @ WT[128x128] (+bias)(+relu) ----------------

__global__ __launch_bounds__(256) void k_gemm128(const float* __restrict__ A, const float* __restrict__ WT,
                                                 const float* __restrict__ bias, float* __restrict__ out,
                                                 int relu) {
    __shared__ float As[32][33];
    __shared__ float Bs[32][128];
    int tid = threadIdx.x;
    int tx = tid & 31, ty = tid >> 5;
    int row0 = blockIdx.x * 32;
    float acc[4][4] = {};
    for (int k0 = 0; k0 < 128; k0 += 32) {
        {
            int r = tid >> 3, k = (tid & 7) << 2;
            float4 v = *(const float4*)&A[(row0 + r) * HH + k0 + k];
            As[r][k] = v.x; As[r][k + 1] = v.y; As[r][k + 2] = v.z; As[r][k + 3] = v.w;
        }
#pragma unroll
        for (int i = 0; i < 4; i++) {
            int kk = (tid >> 5) + i * 8;
            int c = (tid & 31) << 2;
            *(float4*)&Bs[kk][c] = *(const float4*)&WT[(k0 + kk) * HH + c];
        }
        __syncthreads();
#pragma unroll 8
        for (int kk = 0; kk < 32; kk++) {
            float a0 = As[ty * 4 + 0][kk], a1 = As[ty * 4 + 1][kk];
            float a2 = As[ty * 4 + 2][kk], a3 = As[ty * 4 + 3][kk];
            float4 b = *(const float4*)&Bs[kk][tx * 4];
            acc[0][0] = fmaf(a0, b.x, acc[0][0]); acc[0][1] = fmaf(a0, b.y, acc[0][1]);
            acc[0][2] = fmaf(a0, b.z, acc[0][2]); acc[0][3] = fmaf(a0, b.w, acc[0][3]);
            acc[1][0] = fmaf(a1, b.x, acc[1][0]); acc[1][1] = fmaf(a1, b.y, acc[1][1]);
            acc[1][2] = fmaf(a1, b.z, acc[1][2]); acc[1][3] = fmaf(a1, b.w, acc[1][3]);
            acc[2][0] = fmaf(a2, b.x, acc[2][0]); acc[2][1] = fmaf(a2, b.y, acc[2][1]);
            acc[2][2] = fmaf(a2, b.z, acc[2][2]); acc[2][3] = fmaf(a2, b.w, acc[2][3]);
            acc[3][0] = fmaf(a3, b.x, acc[3][0]); acc[3][1] = fmaf(a3, b.y, acc[3][1]);
            acc[3][2] = fmaf(a3, b.z, acc[3][2]); acc[3][3] = fmaf(a3, b.w, acc[3][3]);
        }
        __syncthreads();
    }
#pragma unroll
    for (int i = 0; i < 4; i++) {
        float4 v = make_float4(acc[i][0], acc[i][1], acc[i][2], acc[i][3]);
        if (bias) {
            v.x += bias[tx * 4]; v.y += bias[tx * 4 + 1];
            v.z += bias[tx * 4 + 2]; v.w += bias[tx * 4 + 3];
        }
        if (relu) {
            v.x = fmaxf(v.x, 0.f); v.y = fmaxf(v.y, 0.f);
            v.z = fmaxf(v.z, 0.f); v.w = fmaxf(v.w, 0.f);
        }
        *(float4*)&out[(row0 + ty * 4 + i) * HH + tx * 4] = v;
    }
}

// Ht/Hs projections of h3, emitted as 3-plane split-bf16 (hi/mid/lo), chunk-major
// [chunk(4)][NN][32] per plane. y=0 -> Ht (tgt_w), y=1 -> Hs (src_w).
__global__ __launch_bounds__(256) void k_gemmHtHs(const float* __restrict__ A, const float* __restrict__ T,
                                                  unsigned short* __restrict__ HtH, unsigned short* __restrict__ HtM,
                                                  unsigned short* __restrict__ HtL, unsigned short* __restrict__ HsH,
                                                  unsigned short* __restrict__ HsM, unsigned short* __restrict__ HsL) {
    __shared__ float As[32][33];
    __shared__ float Bs[32][128];
    int which = blockIdx.y;
    const float* WT = (which == 0) ? (T + 4 * 16384) : (T + 3 * 16384);
    int tid = threadIdx.x;
    int tx = tid & 31, ty = tid >> 5;
    int row0 = blockIdx.x * 32;
    float acc[4][4] = {};
    for (int k0 = 0; k0 < 128; k0 += 32) {
        {
            int r = tid >> 3, k = (tid & 7) << 2;
            float4 v = *(const float4*)&A[(row0 + r) * HH + k0 + k];
            As[r][k] = v.x; As[r][k + 1] = v.y; As[r][k + 2] = v.z; As[r][k + 3] = v.w;
        }
#pragma unroll
        for (int i = 0; i < 4; i++) {
            int kk = (tid >> 5) + i * 8;
            int c = (tid & 31) << 2;
            *(float4*)&Bs[kk][c] = *(const float4*)&WT[(k0 + kk) * HH + c];
        }
        __syncthreads();
#pragma unroll 8
        for (int kk = 0; kk < 32; kk++) {
            float a0 = As[ty * 4 + 0][kk], a1 = As[ty * 4 + 1][kk];
            float a2 = As[ty * 4 + 2][kk], a3 = As[ty * 4 + 3][kk];
            float4 b = *(const float4*)&Bs[kk][tx * 4];
            acc[0][0] = fmaf(a0, b.x, acc[0][0]); acc[0][1] = fmaf(a0, b.y, acc[0][1]);
            acc[0][2] = fmaf(a0, b.z, acc[0][2]); acc[0][3] = fmaf(a0, b.w, acc[0][3]);
            acc[1][0] = fmaf(a1, b.x, acc[1][0]); acc[1][1] = fmaf(a1, b.y, acc[1][1]);
            acc[1][2] = fmaf(a1, b.z, acc[1][2]); acc[1][3] = fmaf(a1, b.w, acc[1][3]);
            acc[2][0] = fmaf(a2, b.x, acc[2][0]); acc[2][1] = fmaf(a2, b.y, acc[2][1]);
            acc[2][2] = fmaf(a2, b.z, acc[2][2]); acc[2][3] = fmaf(a2, b.w, acc[2][3]);
            acc[3][0] = fmaf(a3, b.x, acc[3][0]); acc[3][1] = fmaf(a3, b.y, acc[3][1]);
            acc[3][2] = fmaf(a3, b.z, acc[3][2]); acc[3][3] = fmaf(a3, b.w, acc[3][3]);
        }
        __syncthreads();
    }
    unsigned short* Ph = (which == 0) ? HtH : HsH;
    unsigned short* Pm = (which == 0) ? HtM : HsM;
    unsigned short* Pl = (which == 0) ? HtL : HsL;
    int chunk = tx >> 3;              // output col j = stage1's k; chunk = j>>5
    int cic = (tx * 4) & 31;          // col within chunk
#pragma unroll
    for (int i = 0; i < 4; i++) {
        int row = row0 + ty * 4 + i;
        size_t off = ((size_t)chunk * NN + row) * 32 + cic;
        unsigned short h[4], m[4], lo[4];
#pragma unroll
        for (int jj = 0; jj < 4; jj++) {
            float val = acc[i][jj];
            unsigned short hb = f2bf(val);
            float r1 = val - bf2f(hb);        // exact
            unsigned short mb = f2bf(r1);
            float r2 = r1 - bf2f(mb);         // exact
            h[jj] = hb; m[jj] = mb; lo[jj] = f2bf(r2);
        }
        *(uint2*)&Ph[off] = make_uint2((unsigned)h[0] | ((unsigned)h[1] << 16),
                                       (unsigned)h[2] | ((unsigned)h[3] << 16));
        *(uint2*)&Pm[off] = make_uint2((unsigned)m[0] | ((unsigned)m[1] << 16),
                                       (unsigned)m[2] | ((unsigned)m[3] << 16));
        *(uint2*)&Pl[off] = make_uint2((unsigned)lo[0] | ((unsigned)lo[1] << 16),
                                       (unsigned)lo[2] | ((unsigned)lo[3] << 16));
    }
}

// ---------------- candidate counts + valid flags ----------------

__global__ __launch_bounds__(256) void k_cnt_valid(const int* __restrict__ depth, const float* __restrict__ x,
                                                   int* __restrict__ cnt, float* __restrict__ out) {
    int v = blockIdx.x * 256 + threadIdx.x;
    if (v >= NN) return;
    int limit = depth[v] + 1;   // depth[v]-1+DEPTH_PERTURB
    int lo = 0, hi = NN;
    while (lo < hi) { int mid = (lo + hi) >> 1; if (depth[mid] <= limit) lo = mid + 1; else hi = mid; }
    cnt[v] = lo;
    int type = (int)(x[v * 2] + 0.5f);
    bool tv = (depth[v] >= 1) && (type != 0);
    out[4 * NN * 2 + v * 2 + 0] = (tv && lo >= 1) ? 1.0f : 0.0f;
    out[4 * NN * 2 + v * 2 + 1] = (tv && type == 2 && lo >= 2) ? 1.0f : 0.0f;
}

// ---------------- active tile list (one wave) ----------------

__global__ __launch_bounds__(64) void k_tiles(const int* __restrict__ cnt, int* __restrict__ nact,
                                              int* __restrict__ tlist, int* __restrict__ ntiles) {
    int lane = threadIdx.x;   // 0..63, one per 128-row v-block
    int cmax = cnt[lane * 128 + 127];
    int n = (cmax + SEG - 1) / SEG;
    nact[lane] = n;
    int x = n;
    for (int off = 1; off < 64; off <<= 1) {
        int y = __shfl_up(x, off, 64);
        if (lane >= off) x += y;
    }
    int base = x - n;
    for (int s = 0; s < n; s++) tlist[base + s] = (lane << 8) | s;
    if (lane == 63) *ntiles = x;
}

// ---------------- fused masked GEMM + top-2 (stage 1, 3-plane split-bf16 MFMA) ----------------
// Persistent blocks; 4 independent waves/block, each owns 32 v-rows of the 128-row tile.
// No LDS in the main loop. Split: a*b = hh + (hm+mh) + (hl+lh+mm) + O(2^-27) dropped.

__global__ __launch_bounds__(256) void k_top2_stage1(
    const unsigned short* __restrict__ HtH, const unsigned short* __restrict__ HtM,
    const unsigned short* __restrict__ HtL, const unsigned short* __restrict__ HsH,
    const unsigned short* __restrict__ HsM, const unsigned short* __restrict__ HsL,
    const int* __restrict__ cnt, const int* __restrict__ tlist,
    const int* __restrict__ ntiles, int* __restrict__ tctr,
    float* __restrict__ pval, int* __restrict__ pidx) {
    __shared__ int tsh;
    int tid = threadIdx.x;
    int wave = tid >> 6, lane = tid & 63;
    int l = lane & 15, quad = lane >> 4;
    int nt = *ntiles;
    for (;;) {
        if (tid == 0) tsh = atomicAdd(tctr, 1);
        __syncthreads();
        int t = tsh;
        __syncthreads();
        if (t >= nt) return;
        int code = tlist[t];
        int v0 = (code >> 8) * 128;
        int seg = code & 255;
        int ub0 = seg * SEG;
        int vbase = v0 + wave * 32;
        // preload A fragments: [vsub][chunk][hi|mid|lo]; A[m=lane&15][k=quad*8+j]
        bf16x8 afr[2][4][3];
#pragma unroll
        for (int vs = 0; vs < 2; vs++)
#pragma unroll
            for (int c = 0; c < 4; c++) {
                size_t off = ((size_t)c * NN + (vbase + vs * 16 + l)) * 32 + quad * 8;
                afr[vs][c][0] = *(const bf16x8*)&HtH[off];
                afr[vs][c][1] = *(const bf16x8*)&HtM[off];
                afr[vs][c][2] = *(const bf16x8*)&HtL[off];
            }
        // C/D layout (16x16x32): col(u) = lane&15, row(v) = quad*4 + reg
        int creg[8];
#pragma unroll
        for (int i = 0; i < 8; i++)
            creg[i] = cnt[vbase + (i >> 2) * 16 + quad * 4 + (i & 3)];
        float t1v[8], t2v[8]; int t1i[8], t2i[8];
#pragma unroll
        for (int i = 0; i < 8; i++) { t1v[i] = NEGV; t2v[i] = NEGV; t1i[i] = 0x7fffffff; t2i[i] = 0x7fffffff; }
        int cmax = cnt[v0 + 127];
        int uend = ub0 + SEG; if (uend > cmax) uend = cmax;
        for (int u0 = ub0; u0 < uend; u0 += 16) {
            int ur = u0 + l; if (ur > NN - 1) ur = NN - 1;   // clamp tail loads (masked below)
            f32x4 acc0 = {0.f, 0.f, 0.f, 0.f}, acc1 = {0.f, 0.f, 0.f, 0.f};
#pragma unroll
            for (int c = 0; c < 4; c++) {
                size_t boff = ((size_t)c * NN + ur) * 32 + quad * 8;
                bf16x8 bh = *(const bf16x8*)&HsH[boff];
                bf16x8 bm = *(const bf16x8*)&HsM[boff];
                bf16x8 bl = *(const bf16x8*)&HsL[boff];
                // hh
                acc0 = __builtin_amdgcn_mfma_f32_16x16x32_bf16(afr[0][c][0], bh, acc0, 0, 0, 0);
                acc1 = __builtin_amdgcn_mfma_f32_16x16x32_bf16(afr[1][c][0], bh, acc1, 0, 0, 0);
                // hm + mh
                acc0 = __builtin_amdgcn_mfma_f32_16x16x32_bf16(afr[0][c][0], bm, acc0, 0, 0, 0);
                acc1 = __builtin_amdgcn_mfma_f32_16x16x32_bf16(afr[1][c][0], bm, acc1, 0, 0, 0);
                acc0 = __builtin_amdgcn_mfma_f32_16x16x32_bf16(afr[0][c][1], bh, acc0, 0, 0, 0);
                acc1 = __builtin_amdgcn_mfma_f32_16x16x32_bf16(afr[1][c][1], bh, acc1, 0, 0, 0);
                // hl + lh + mm
                acc0 = __builtin_amdgcn_mfma_f32_16x16x32_bf16(afr[0][c][0], bl, acc0, 0, 0, 0);
                acc1 = __builtin_amdgcn_mfma_f32_16x16x32_bf16(afr[1][c][0], bl, acc1, 0, 0, 0);
                acc0 = __builtin_amdgcn_mfma_f32_16x16x32_bf16(afr[0][c][2], bh, acc0, 0, 0, 0);
                acc1 = __builtin_amdgcn_mfma_f32_16x16x32_bf16(afr[1][c][2], bh, acc1, 0, 0, 0);
                acc0 = __builtin_amdgcn_mfma_f32_16x16x32_bf16(afr[0][c][1], bm, acc0, 0, 0, 0);
                acc1 = __builtin_amdgcn_mfma_f32_16x16x32_bf16(afr[1][c][1], bm, acc1, 0, 0, 0);
            }
            int u = u0 + l;
#pragma unroll
            for (int i = 0; i < 8; i++) {
                float sv = (i < 4) ? acc0[i & 3] : acc1[i & 3];
                float val = (u < creg[i]) ? sv : NEGV;   // masked: NEG with real index (top_k tie semantics)
                if (val > t1v[i] || (val == t1v[i] && u < t1i[i])) {
                    t2v[i] = t1v[i]; t2i[i] = t1i[i]; t1v[i] = val; t1i[i] = u;
                } else if (val > t2v[i] || (val == t2v[i] && u < t2i[i])) {
                    t2v[i] = val; t2i[i] = u;
                }
            }
        }
        // merge top-2 across the 16 lanes of each quad group (disjoint u sets)
#pragma unroll
        for (int m = 1; m <= 8; m <<= 1) {
#pragma unroll
            for (int i = 0; i < 8; i++) {
                float ov1 = __shfl_xor(t1v[i], m, 64);
                int   oi1 = __shfl_xor(t1i[i], m, 64);
                float ov2 = __shfl_xor(t2v[i], m, 64);
                int   oi2 = __shfl_xor(t2i[i], m, 64);
                bool b1 = (ov1 > t1v[i]) || (ov1 == t1v[i] && oi1 < t1i[i]);
                float w1v = b1 ? ov1 : t1v[i]; int w1i = b1 ? oi1 : t1i[i];
                float l1v = b1 ? t1v[i] : ov1; int l1i = b1 ? t1i[i] : oi1;
                float c2v = b1 ? ov2 : t2v[i]; int c2i = b1 ? oi2 : t2i[i];
                bool b2 = (l1v > c2v) || (l1v == c2v && l1i < c2i);
                t1v[i] = w1v; t1i[i] = w1i;
                t2v[i] = b2 ? l1v : c2v; t2i[i] = b2 ? l1i : c2i;
            }
        }
        if (l == 0) {
#pragma unroll
            for (int i = 0; i < 8; i++) {
                int v = vbase + (i >> 2) * 16 + quad * 4 + (i & 3);
                int o = (v * NSEG + seg) * 2;
                pval[o] = t1v[i];     pidx[o] = t1i[i];
                pval[o + 1] = t2v[i]; pidx[o + 1] = t2i[i];
            }
        }
    }
}

// ---------------- stage 2: merge segment partials, emit top_vals/top_idx ----------------

__global__ __launch_bounds__(256) void k_top2_merge(const float* __restrict__ pval, const int* __restrict__ pidx,
                                                    const int* __restrict__ nact,
                                                    float* __restrict__ out, int* __restrict__ tidx) {
    int v = blockIdx.x * 256 + threadIdx.x;
    if (v >= NN) return;
    int na = nact[v >> 7];
    float v1 = NEGV, v2 = NEGV; int i1 = 0x7fffffff, i2 = 0x7fffffff;
    if (na == 0) { i1 = 0; i2 = 1; }
    for (int t = 0; t < na * 2; t++) {
        float val = pval[v * (NSEG * 2) + t]; int idx = pidx[v * (NSEG * 2) + t];
        if (val > v1 || (val == v1 && idx < i1)) { v2 = v1; i2 = i1; v1 = val; i1 = idx; }
        else if (val > v2 || (val == v2 && idx < i2)) { v2 = val; i2 = idx; }
    }
    out[v * 2 + 0] = v1; out[v * 2 + 1] = v2;                    // top_vals
    out[2 * NN * 2 + v * 2 + 0] = (float)i1;                     // top_idx
    out[2 * NN * 2 + v * 2 + 1] = (float)i2;
    tidx[v * 2] = i1; tidx[v * 2 + 1] = i2;
}

// ---------------- inversion-bit epilogue: logit = inv2 . relu(P[u]+Q[v]+cz) + b ----------------

__global__ __launch_bounds__(256) void k_inv(const float* __restrict__ P, const float* __restrict__ Q,
                                             const float* __restrict__ cz, const float* __restrict__ w2,
                                             const float* __restrict__ b2, const int* __restrict__ tidx,
                                             float* __restrict__ out) {
    int gid = blockIdx.x * 256 + threadIdx.x;
    int wid = gid >> 6;
    int lane = gid & 63;
    if (wid >= NN * 2) return;
    int v = wid >> 1;
    int u = tidx[wid]; if (u > NN - 1) u = NN - 1; if (u < 0) u = 0;
    float h0 = fmaxf(P[u * HH + lane] + Q[v * HH + lane] + cz[lane], 0.f);
    float h1 = fmaxf(P[u * HH + 64 + lane] + Q[v * HH + 64 + lane] + cz[64 + lane], 0.f);
    float p = h0 * w2[lane] + h1 * w2[64 + lane];
    for (int off = 32; off >= 1; off >>= 1) p += __shfl_down(p, off, 64);
    if (lane == 0) {
        float logit = p + b2[0];
        out[NN * 2 + wid] = logit;                               // inv_logit
        out[3 * NN * 2 + wid] = (logit > 0.f) ? 1.f : 0.f;       // inv_bit
    }
}

// ---------------- launch ----------------

extern "C" void kernel_launch(void* const* d_in, const int* in_sizes, int n_in,
                              void* d_out, int out_size, void* d_ws, size_t ws_size,
                              hipStream_t stream) {
    const float* x       = (const float*)d_in[0];
    const float* z       = (const float*)d_in[1];
    const int*   eidx    = (const int*)d_in[2];
    const int*   depth   = (const int*)d_in[3];
    const float* conv1_w = (const float*)d_in[4];
    const float* conv1_b = (const float*)d_in[5];
    const float* conv2_w = (const float*)d_in[6];
    const float* conv2_b = (const float*)d_in[7];
    const float* np1_w   = (const float*)d_in[8];
    const float* np1_b   = (const float*)d_in[9];
    const float* np2_w   = (const float*)d_in[10];
    const float* np2_b   = (const float*)d_in[11];
    const float* src_w   = (const float*)d_in[12];
    const float* tgt_w   = (const float*)d_in[13];
    const float* inv1_w  = (const float*)d_in[14];
    const float* inv1_b  = (const float*)d_in[15];
    const float* inv2_w  = (const float*)d_in[16];
    const float* inv2_b  = (const float*)d_in[17];
    float* out = (float*)d_out;
    float* wsf = (float*)d_ws;

    const int NH = NN * HH;   // 1,048,576
    // Region map (floats):
    //   [0,NH)        h3 (final node embedding)
    //   [NH,4NH)      6 split-bf16 planes (2MB each) during stage1;
    //                 earlier: A=[NH,2NH) B=[2NH,3NH) GCN temps; later: P=[NH,2NH) Q=[2NH,3NH)
    //   [4NH,5NH)     t (np1 out); later pval/pidx
    //   [5NH,...)     T, c1, cz, rsq, dinv, ints
    float* h3 = wsf;
    float* A  = wsf + (size_t)NH;
    float* B  = wsf + 2 * (size_t)NH;
    float* C  = wsf + 4 * (size_t)NH;
    unsigned short* PLN = (unsigned short*)(wsf + (size_t)NH);
    unsigned short* HtH = PLN + 0 * (size_t)NH;
    unsigned short* HtM = PLN + 1 * (size_t)NH;
    unsigned short* HtL = PLN + 2 * (size_t)NH;
    unsigned short* HsH = PLN + 3 * (size_t)NH;
    unsigned short* HsM = PLN + 4 * (size_t)NH;
    unsigned short* HsL = PLN + 5 * (size_t)NH;
    float* P = wsf + (size_t)NH;         // after stage1 (planes dead)
    float* Q = wsf + 2 * (size_t)NH;
    float* pval = wsf + 4 * (size_t)NH;  // NN*NSEG*2 = 524288 floats
    int*   pidx = (int*)(pval + NN * NSEG * 2);
    float* T  = wsf + 5 * (size_t)NH;
    float* c1 = T + 7 * 16384;
    float* cz = c1 + 128;
    float* rsq  = cz + 128;
    float* dinv = rsq + NN;
    int* degi   = (int*)(dinv + NN);
    int* rowptr = degi + NN;             // NN+1
    int* cursor = rowptr + NN + 1;
    int* cnt    = cursor + NN;
    int* nact   = cnt + NN;              // 64
    int* ntiles = nact + 64;
    int* tctr   = ntiles + 1;
    int* tidx   = tctr + 1;              // 2*NN
    int* tlist  = tidx + 2 * NN;         // <= 2048
    int* ecsr   = tlist + 2048;          // EE

    const int* esrc = eidx;
    const int* edst = eidx + EE;

    hipMemsetAsync(degi, 0, NN * sizeof(int), stream);
    hipMemsetAsync(cursor, 0, NN * sizeof(int), stream);
    hipMemsetAsync(tctr, 0, sizeof(int), stream);
    k_prep<<<dim3(64, 8), 256, 0, stream>>>(conv2_w, np1_w, np2_w, src_w, tgt_w, inv1_w,
                                            np1_b, inv1_b, z, T, c1, cz);
    k_deg<<<EE / 256, 256, 0, stream>>>(edst, degi);
    k_rsq<<<NN / 256, 256, 0, stream>>>(degi, dinv, rsq);
    k_scan<<<1, 1024, 0, stream>>>(degi, rowptr);
    k_fill<<<EE / 256, 256, 0, stream>>>(esrc, edst, rowptr, cursor, ecsr);
    k_xw1<<<NH / 256, 256, 0, stream>>>(x, conv1_w, A);
    k_gather<<<NN * 64 / 256, 256, 0, stream>>>(rowptr, ecsr, rsq, dinv, A, conv1_b, B);   // h1
    k_gemm128<<<256, 256, 0, stream>>>(B, T + 0 * 16384, nullptr, A, 0);                   // xw2
    k_gather<<<NN * 64 / 256, 256, 0, stream>>>(rowptr, ecsr, rsq, dinv, A, conv2_b, B);   // h2
    k_gemm128<<<256, 256, 0, stream>>>(B, T + 1 * 16384, c1, C, 1);        // t = relu(h2@np1h^T + c1)
    k_gemm128<<<256, 256, 0, stream>>>(C, T + 2 * 16384, np2_b, h3, 0);    // h3
    k_gemmHtHs<<<dim3(256, 2), 256, 0, stream>>>(h3, T, HtH, HtM, HtL, HsH, HsM, HsL);
    k_cnt_valid<<<NN / 256, 256, 0, stream>>>(depth, x, cnt, out);
    k_tiles<<<1, 64, 0, stream>>>(cnt, nact, tlist, ntiles);
    k_top2_stage1<<<768, 256, 0, stream>>>(HtH, HtM, HtL, HsH, HsM, HsL,
                                           cnt, tlist, ntiles, tctr, pval, pidx);
    k_top2_merge<<<NN / 256, 256, 0, stream>>>(pval, pidx, nact, out, tidx);
    k_gemm128<<<256, 256, 0, stream>>>(h3, T + 5 * 16384, nullptr, P, 0);  // P = h3@inv1a^T
    k_gemm128<<<256, 256, 0, stream>>>(h3, T + 6 * 16384, nullptr, Q, 0);  // Q = h3@inv1b^T
    k_inv<<<(NN * 2 * 64) / 256, 256, 0, stream>>>(P, Q, cz, inv2_w, inv2_b, tidx, out);
}

// Round 6
// 391.574 us; speedup vs baseline: 1.0810x; 1.0810x over previous
//
#include <hip/hip_runtime.h>

#define NN 8192
#define EE 131072
#define HH 128
#define NEGV -1.0e30f
#define SEG 256
#define NSEG (NN / SEG)   // 32

typedef __attribute__((ext_vector_type(8))) short bf16x8;
typedef __attribute__((ext_vector_type(4))) float f32x4;

__device__ __forceinline__ unsigned short f2bf(float f) {
    unsigned int u = __float_as_uint(f);
    unsigned int r = u + 0x7fffu + ((u >> 16) & 1u);
    return (unsigned short)(r >> 16);
}
__device__ __forceinline__ float bf2f(unsigned short b) {
    return __uint_as_float((unsigned int)b << 16);
}

// ---------------- degree (int) ----------------

__global__ __launch_bounds__(256) void k_deg(const int* __restrict__ dst, int* __restrict__ degi) {
    int t = blockIdx.x * 256 + threadIdx.x;
    if (t < EE) atomicAdd(&degi[dst[t]], 1);
}

__global__ __launch_bounds__(256) void k_rsq(const int* __restrict__ degi, float* __restrict__ dinv,
                                             float* __restrict__ rsq) {
    int t = blockIdx.x * 256 + threadIdx.x;
    if (t < NN) {
        double d = (double)(degi[t] + 1);   // +1 self loop
        dinv[t] = (float)(1.0 / d);
        rsq[t] = (float)(1.0 / sqrt(d));
    }
}

// exclusive scan of degi[NN] -> rowptr[NN+1]; single block of 1024, 8 elems/thread
__global__ __launch_bounds__(1024) void k_scan(const int* __restrict__ degi, int* __restrict__ rowptr) {
    __shared__ int ls[1024];
    int tid = threadIdx.x;
    int base = tid * 8;
    int loc[8]; int s = 0;
#pragma unroll
    for (int i = 0; i < 8; i++) { loc[i] = s; s += degi[base + i]; }
    ls[tid] = s; __syncthreads();
    int tot = s;
    for (int d = 1; d < 1024; d <<= 1) {
        int v = (tid >= d) ? ls[tid - d] : 0;
        __syncthreads();
        ls[tid] += v;
        __syncthreads();
    }
    int pre = ls[tid] - tot;
#pragma unroll
    for (int i = 0; i < 8; i++) rowptr[base + i] = pre + loc[i];
    if (tid == 1023) rowptr[NN] = pre + tot;
}

__global__ __launch_bounds__(256) void k_fill(const int* __restrict__ src, const int* __restrict__ dst,
                                              const int* __restrict__ rowptr, int* __restrict__ cursor,
                                              int* __restrict__ ecsr) {
    int t = blockIdx.x * 256 + threadIdx.x;
    if (t < EE) {
        int d = dst[t];
        int pos = atomicAdd(&cursor[d], 1);
        ecsr[rowptr[d] + pos] = src[t];
    }
}

// ---------------- GCN: xw for conv1, gather-aggregate (fused bias+relu) ----------------

__global__ __launch_bounds__(256) void k_xw1(const float* __restrict__ x, const float* __restrict__ w,
                                             float* __restrict__ out) {
    int t = blockIdx.x * 256 + threadIdx.x;   // N*H threads
    int i = t >> 7, j = t & 127;
    out[t] = x[i * 2] * w[j * 2] + x[i * 2 + 1] * w[j * 2 + 1];
}

__global__ __launch_bounds__(256) void k_gather(const int* __restrict__ rowptr, const int* __restrict__ ecsr,
                                                const float* __restrict__ rsq, const float* __restrict__ dinv,
                                                const float* __restrict__ xw, const float* __restrict__ bias,
                                                float* __restrict__ out) {
    int g = blockIdx.x * 256 + threadIdx.x;
    int d = g >> 6, lane = g & 63;
    if (d >= NN) return;
    int s0 = rowptr[d], s1 = rowptr[d + 1];
    float rd = rsq[d];
    float a0 = 0.f, a1 = 0.f;
    for (int sl = s0; sl < s1; sl++) {
        int s = ecsr[sl];                       // wave-uniform scalar load
        float f = rsq[s] * rd;
        a0 = fmaf(f, xw[s * HH + lane], a0);    // coalesced 256B row segment
        a1 = fmaf(f, xw[s * HH + 64 + lane], a1);
    }
    float di = dinv[d];
    a0 = fmaf(xw[d * HH + lane], di, a0) + bias[lane];
    a1 = fmaf(xw[d * HH + 64 + lane], di, a1) + bias[64 + lane];
    out[d * HH + lane] = fmaxf(a0, 0.f);
    out[d * HH + 64 + lane] = fmaxf(a1, 0.f);
}

// ---------------- weight prep: transposes + folded-z biases ----------------
// T holds 7 transposed 128x128 mats: 0 conv2, 1 np1(h-part), 2 np2, 3 src, 4 tgt, 5 inv1(h_u), 6 inv1(h_v)

__global__ __launch_bounds__(256) void k_prep(const float* __restrict__ conv2_w, const float* __restrict__ np1_w,
                                              const float* __restrict__ np2_w, const float* __restrict__ src_w,
                                              const float* __restrict__ tgt_w, const float* __restrict__ inv1_w,
                                              const float* __restrict__ np1_b, const float* __restrict__ inv1_b,
                                              const float* __restrict__ z, float* __restrict__ T,
                                              float* __restrict__ c1, float* __restrict__ cz) {
    int y = blockIdx.y;
    if (y < 7) {
        int t = blockIdx.x * 256 + threadIdx.x;   // 16384 per matrix
        int j = t >> 7, k = t & 127;
        const float* W; int stride, off;
        switch (y) {
            case 0:  W = conv2_w; stride = 128; off = 0;   break;
            case 1:  W = np1_w;   stride = 256; off = 0;   break;
            case 2:  W = np2_w;   stride = 128; off = 0;   break;
            case 3:  W = src_w;   stride = 128; off = 0;   break;
            case 4:  W = tgt_w;   stride = 128; off = 0;   break;
            case 5:  W = inv1_w;  stride = 384; off = 0;   break;
            default: W = inv1_w;  stride = 384; off = 128; break;
        }
        T[y * 16384 + k * 128 + j] = W[j * stride + off + k];
    } else if (blockIdx.x == 0) {
        int tid = threadIdx.x;
        if (tid < 128) {
            float s = np1_b[tid];
            for (int k = 0; k < 128; k++) s += z[k] * np1_w[tid * 256 + 128 + k];
            c1[tid] = s;
        } else {
            int j = tid - 128;
            float s = inv1_b[j];
            for (int k = 0; k < 128; k++) s += z[k] * inv1_w[j * 384 + 256 + k];
            cz[j] = s;
        }
    }
}

// ---------------- generic [8192x128] @ WT[128x128] (+bias)(+relu) ----------------

__global__ __launch_bounds__(256) void k_gemm128(const float* __restrict__ A, const float* __restrict__ WT,
                                                 const float* __restrict__ bias, float* __restrict__ out,
                                                 int relu) {
    __shared__ float As[32][33];
    __shared__ float Bs[32][128];
    int tid = threadIdx.x;
    int tx = tid & 31, ty = tid >> 5;
    int row0 = blockIdx.x * 32;
    float acc[4][4] = {};
    for (int k0 = 0; k0 < 128; k0 += 32) {
        {
            int r = tid >> 3, k = (tid & 7) << 2;
            float4 v = *(const float4*)&A[(row0 + r) * HH + k0 + k];
            As[r][k] = v.x; As[r][k + 1] = v.y; As[r][k + 2] = v.z; As[r][k + 3] = v.w;
        }
#pragma unroll
        for (int i = 0; i < 4; i++) {
            int kk = (tid >> 5) + i * 8;
            int c = (tid & 31) << 2;
            *(float4*)&Bs[kk][c] = *(const float4*)&WT[(k0 + kk) * HH + c];
        }
        __syncthreads();
#pragma unroll 8
        for (int kk = 0; kk < 32; kk++) {
            float a0 = As[ty * 4 + 0][kk], a1 = As[ty * 4 + 1][kk];
            float a2 = As[ty * 4 + 2][kk], a3 = As[ty * 4 + 3][kk];
            float4 b = *(const float4*)&Bs[kk][tx * 4];
            acc[0][0] = fmaf(a0, b.x, acc[0][0]); acc[0][1] = fmaf(a0, b.y, acc[0][1]);
            acc[0][2] = fmaf(a0, b.z, acc[0][2]); acc[0][3] = fmaf(a0, b.w, acc[0][3]);
            acc[1][0] = fmaf(a1, b.x, acc[1][0]); acc[1][1] = fmaf(a1, b.y, acc[1][1]);
            acc[1][2] = fmaf(a1, b.z, acc[1][2]); acc[1][3] = fmaf(a1, b.w, acc[1][3]);
            acc[2][0] = fmaf(a2, b.x, acc[2][0]); acc[2][1] = fmaf(a2, b.y, acc[2][1]);
            acc[2][2] = fmaf(a2, b.z, acc[2][2]); acc[2][3] = fmaf(a2, b.w, acc[2][3]);
            acc[3][0] = fmaf(a3, b.x, acc[3][0]); acc[3][1] = fmaf(a3, b.y, acc[3][1]);
            acc[3][2] = fmaf(a3, b.z, acc[3][2]); acc[3][3] = fmaf(a3, b.w, acc[3][3]);
        }
        __syncthreads();
    }
#pragma unroll
    for (int i = 0; i < 4; i++) {
        float4 v = make_float4(acc[i][0], acc[i][1], acc[i][2], acc[i][3]);
        if (bias) {
            v.x += bias[tx * 4]; v.y += bias[tx * 4 + 1];
            v.z += bias[tx * 4 + 2]; v.w += bias[tx * 4 + 3];
        }
        if (relu) {
            v.x = fmaxf(v.x, 0.f); v.y = fmaxf(v.y, 0.f);
            v.z = fmaxf(v.z, 0.f); v.w = fmaxf(v.w, 0.f);
        }
        *(float4*)&out[(row0 + ty * 4 + i) * HH + tx * 4] = v;
    }
}

// Ht/Hs projections of h3, emitted as 3-plane split-bf16 (hi/mid/lo), plane-interleaved
// chunk-major: PP[((chunk*NN + row))*96 + plane*32 + colInChunk]. y=0 -> Ht, y=1 -> Hs.
__global__ __launch_bounds__(256) void k_gemmHtHs(const float* __restrict__ A, const float* __restrict__ T,
                                                  unsigned short* __restrict__ HtP,
                                                  unsigned short* __restrict__ HsP) {
    __shared__ float As[32][33];
    __shared__ float Bs[32][128];
    int which = blockIdx.y;
    const float* WT = (which == 0) ? (T + 4 * 16384) : (T + 3 * 16384);
    int tid = threadIdx.x;
    int tx = tid & 31, ty = tid >> 5;
    int row0 = blockIdx.x * 32;
    float acc[4][4] = {};
    for (int k0 = 0; k0 < 128; k0 += 32) {
        {
            int r = tid >> 3, k = (tid & 7) << 2;
            float4 v = *(const float4*)&A[(row0 + r) * HH + k0 + k];
            As[r][k] = v.x; As[r][k + 1] = v.y; As[r][k + 2] = v.z; As[r][k + 3] = v.w;
        }
#pragma unroll
        for (int i = 0; i < 4; i++) {
            int kk = (tid >> 5) + i * 8;
            int c = (tid & 31) << 2;
            *(float4*)&Bs[kk][c] = *(const float4*)&WT[(k0 + kk) * HH + c];
        }
        __syncthreads();
#pragma unroll 8
        for (int kk = 0; kk < 32; kk++) {
            float a0 = As[ty * 4 + 0][kk], a1 = As[ty * 4 + 1][kk];
            float a2 = As[ty * 4 + 2][kk], a3 = As[ty * 4 + 3][kk];
            float4 b = *(const float4*)&Bs[kk][tx * 4];
            acc[0][0] = fmaf(a0, b.x, acc[0][0]); acc[0][1] = fmaf(a0, b.y, acc[0][1]);
            acc[0][2] = fmaf(a0, b.z, acc[0][2]); acc[0][3] = fmaf(a0, b.w, acc[0][3]);
            acc[1][0] = fmaf(a1, b.x, acc[1][0]); acc[1][1] = fmaf(a1, b.y, acc[1][1]);
            acc[1][2] = fmaf(a1, b.z, acc[1][2]); acc[1][3] = fmaf(a1, b.w, acc[1][3]);
            acc[2][0] = fmaf(a2, b.x, acc[2][0]); acc[2][1] = fmaf(a2, b.y, acc[2][1]);
            acc[2][2] = fmaf(a2, b.z, acc[2][2]); acc[2][3] = fmaf(a2, b.w, acc[2][3]);
            acc[3][0] = fmaf(a3, b.x, acc[3][0]); acc[3][1] = fmaf(a3, b.y, acc[3][1]);
            acc[3][2] = fmaf(a3, b.z, acc[3][2]); acc[3][3] = fmaf(a3, b.w, acc[3][3]);
        }
        __syncthreads();
    }
    unsigned short* PP = (which == 0) ? HtP : HsP;
    int chunk = tx >> 3;              // output col j = stage1's k; chunk = j>>5
    int cic = (tx * 4) & 31;          // col within chunk
#pragma unroll
    for (int i = 0; i < 4; i++) {
        int row = row0 + ty * 4 + i;
        size_t off = ((size_t)(chunk * NN + row)) * 96 + cic;
        unsigned short h[4], m[4], lo[4];
#pragma unroll
        for (int jj = 0; jj < 4; jj++) {
            float val = acc[i][jj];
            unsigned short hb = f2bf(val);
            float r1 = val - bf2f(hb);        // exact
            unsigned short mb = f2bf(r1);
            float r2 = r1 - bf2f(mb);         // exact
            h[jj] = hb; m[jj] = mb; lo[jj] = f2bf(r2);
        }
        *(uint2*)&PP[off] = make_uint2((unsigned)h[0] | ((unsigned)h[1] << 16),
                                       (unsigned)h[2] | ((unsigned)h[3] << 16));
        *(uint2*)&PP[off + 32] = make_uint2((unsigned)m[0] | ((unsigned)m[1] << 16),
                                            (unsigned)m[2] | ((unsigned)m[3] << 16));
        *(uint2*)&PP[off + 64] = make_uint2((unsigned)lo[0] | ((unsigned)lo[1] << 16),
                                            (unsigned)lo[2] | ((unsigned)lo[3] << 16));
    }
}

// ---------------- candidate counts + valid flags ----------------

__global__ __launch_bounds__(256) void k_cnt_valid(const int* __restrict__ depth, const float* __restrict__ x,
                                                   int* __restrict__ cnt, float* __restrict__ out) {
    int v = blockIdx.x * 256 + threadIdx.x;
    if (v >= NN) return;
    int limit = depth[v] + 1;   // depth[v]-1+DEPTH_PERTURB
    int lo = 0, hi = NN;
    while (lo < hi) { int mid = (lo + hi) >> 1; if (depth[mid] <= limit) lo = mid + 1; else hi = mid; }
    cnt[v] = lo;
    int type = (int)(x[v * 2] + 0.5f);
    bool tv = (depth[v] >= 1) && (type != 0);
    out[4 * NN * 2 + v * 2 + 0] = (tv && lo >= 1) ? 1.0f : 0.0f;
    out[4 * NN * 2 + v * 2 + 1] = (tv && type == 2 && lo >= 2) ? 1.0f : 0.0f;
}

// ---------------- active tile list (64-row v-blocks -> 128 entries) ----------------

__global__ __launch_bounds__(128) void k_tiles(const int* __restrict__ cnt, int* __restrict__ nact,
                                               int* __restrict__ tlist, int* __restrict__ ntiles) {
    __shared__ int ls[128];
    int tid = threadIdx.x;   // 0..127, one per 64-row v-block
    int cmax = cnt[tid * 64 + 63];
    int n = (cmax + SEG - 1) / SEG;
    nact[tid] = n;
    ls[tid] = n; __syncthreads();
    for (int d = 1; d < 128; d <<= 1) {
        int v = (tid >= d) ? ls[tid - d] : 0;
        __syncthreads();
        ls[tid] += v;
        __syncthreads();
    }
    int base = ls[tid] - n;
    for (int s = 0; s < n; s++) tlist[base + s] = (tid << 8) | s;
    if (tid == 127) *ntiles = ls[127];
}

// ---------------- fused masked GEMM + top-2 (stage 1, 3-plane split-bf16 MFMA) ----------------
// Persistent blocks; 4 waves/block, each owns 16 v-rows of a 64-row tile; u in steps of 32
// with two accumulator chains. A fragments (12 x bf16x8 = 48 VGPRs) held in registers —
// launch_bounds(256,3) gives ~170 VGPR headroom so nothing rematerializes in the loop.
// Split product: a*b = hh + hm + mh + hl + lh + mm + O(2^-27) dropped.

__global__ __launch_bounds__(256, 3) void k_top2_stage1(
    const unsigned short* __restrict__ HtP, const unsigned short* __restrict__ HsP,
    const int* __restrict__ cnt, const int* __restrict__ tlist,
    const int* __restrict__ ntiles, int* __restrict__ tctr,
    float* __restrict__ pval, int* __restrict__ pidx) {
    __shared__ int tsh;
    int tid = threadIdx.x;
    int wave = tid >> 6, lane = tid & 63;
    int l = lane & 15, quad = lane >> 4;
    int nt = *ntiles;
    for (;;) {
        if (tid == 0) tsh = atomicAdd(tctr, 1);
        __syncthreads();
        int t = tsh;
        __syncthreads();
        if (t >= nt) return;
        int code = tlist[t];
        int v0 = (code >> 8) * 64;
        int seg = code & 255;
        int ub0 = seg * SEG;
        int vbase = v0 + wave * 16;
        // A fragments: [chunk][hi|mid|lo]; A[m=lane&15][k=quad*8+j]
        bf16x8 afr[4][3];
#pragma unroll
        for (int c = 0; c < 4; c++) {
            size_t ao = ((size_t)(c * NN + vbase + l)) * 96 + quad * 8;
            afr[c][0] = *(const bf16x8*)&HtP[ao];
            afr[c][1] = *(const bf16x8*)&HtP[ao + 32];
            afr[c][2] = *(const bf16x8*)&HtP[ao + 64];
        }
        // C/D layout (16x16x32): col(u) = lane&15, row(v) = quad*4 + reg
        int creg[4];
#pragma unroll
        for (int i = 0; i < 4; i++) creg[i] = cnt[vbase + quad * 4 + i];
        float t1v[4], t2v[4]; int t1i[4], t2i[4];
#pragma unroll
        for (int i = 0; i < 4; i++) { t1v[i] = NEGV; t2v[i] = NEGV; t1i[i] = 0x7fffffff; t2i[i] = 0x7fffffff; }
        int cmax = cnt[v0 + 63];
        int uend = ub0 + SEG; if (uend > cmax) uend = cmax;
        for (int u0 = ub0; u0 < uend; u0 += 32) {
            int uA = u0 + l;          // provably <= NN-1 (u0 <= 8160)
            int uB = u0 + 16 + l;
            f32x4 accA = {0.f, 0.f, 0.f, 0.f}, accB = {0.f, 0.f, 0.f, 0.f};
#pragma unroll
            for (int c = 0; c < 4; c++) {
                size_t bA = ((size_t)(c * NN + uA)) * 96 + quad * 8;
                size_t bB = ((size_t)(c * NN + uB)) * 96 + quad * 8;
                bf16x8 bhA = *(const bf16x8*)&HsP[bA];
                bf16x8 bmA = *(const bf16x8*)&HsP[bA + 32];
                bf16x8 blA = *(const bf16x8*)&HsP[bA + 64];
                bf16x8 bhB = *(const bf16x8*)&HsP[bB];
                bf16x8 bmB = *(const bf16x8*)&HsP[bB + 32];
                bf16x8 blB = *(const bf16x8*)&HsP[bB + 64];
                accA = __builtin_amdgcn_mfma_f32_16x16x32_bf16(afr[c][0], bhA, accA, 0, 0, 0);
                accB = __builtin_amdgcn_mfma_f32_16x16x32_bf16(afr[c][0], bhB, accB, 0, 0, 0);
                accA = __builtin_amdgcn_mfma_f32_16x16x32_bf16(afr[c][0], bmA, accA, 0, 0, 0);
                accB = __builtin_amdgcn_mfma_f32_16x16x32_bf16(afr[c][0], bmB, accB, 0, 0, 0);
                accA = __builtin_amdgcn_mfma_f32_16x16x32_bf16(afr[c][1], bhA, accA, 0, 0, 0);
                accB = __builtin_amdgcn_mfma_f32_16x16x32_bf16(afr[c][1], bhB, accB, 0, 0, 0);
                accA = __builtin_amdgcn_mfma_f32_16x16x32_bf16(afr[c][0], blA, accA, 0, 0, 0);
                accB = __builtin_amdgcn_mfma_f32_16x16x32_bf16(afr[c][0], blB, accB, 0, 0, 0);
                accA = __builtin_amdgcn_mfma_f32_16x16x32_bf16(afr[c][2], bhA, accA, 0, 0, 0);
                accB = __builtin_amdgcn_mfma_f32_16x16x32_bf16(afr[c][2], bhB, accB, 0, 0, 0);
                accA = __builtin_amdgcn_mfma_f32_16x16x32_bf16(afr[c][1], bmA, accA, 0, 0, 0);
                accB = __builtin_amdgcn_mfma_f32_16x16x32_bf16(afr[c][1], bmB, accB, 0, 0, 0);
            }
#pragma unroll
            for (int i = 0; i < 4; i++) {
                int c = creg[i];
                float vA = (uA < c) ? accA[i] : NEGV;   // masked: NEG with real index
                if (vA > t1v[i] || (vA == t1v[i] && uA < t1i[i])) {
                    t2v[i] = t1v[i]; t2i[i] = t1i[i]; t1v[i] = vA; t1i[i] = uA;
                } else if (vA > t2v[i] || (vA == t2v[i] && uA < t2i[i])) {
                    t2v[i] = vA; t2i[i] = uA;
                }
                float vB = (uB < c) ? accB[i] : NEGV;
                if (vB > t1v[i] || (vB == t1v[i] && uB < t1i[i])) {
                    t2v[i] = t1v[i]; t2i[i] = t1i[i]; t1v[i] = vB; t1i[i] = uB;
                } else if (vB > t2v[i] || (vB == t2v[i] && uB < t2i[i])) {
                    t2v[i] = vB; t2i[i] = uB;
                }
            }
        }
        // merge top-2 across the 16 lanes of each quad group (disjoint u sets)
#pragma unroll
        for (int m = 1; m <= 8; m <<= 1) {
#pragma unroll
            for (int i = 0; i < 4; i++) {
                float ov1 = __shfl_xor(t1v[i], m, 64);
                int   oi1 = __shfl_xor(t1i[i], m, 64);
                float ov2 = __shfl_xor(t2v[i], m, 64);
                int   oi2 = __shfl_xor(t2i[i], m, 64);
                bool b1 = (ov1 > t1v[i]) || (ov1 == t1v[i] && oi1 < t1i[i]);
                float w1v = b1 ? ov1 : t1v[i]; int w1i = b1 ? oi1 : t1i[i];
                float l1v = b1 ? t1v[i] : ov1; int l1i = b1 ? t1i[i] : oi1;
                float c2v = b1 ? ov2 : t2v[i]; int c2i = b1 ? oi2 : t2i[i];
                bool b2 = (l1v > c2v) || (l1v == c2v && l1i < c2i);
                t1v[i] = w1v; t1i[i] = w1i;
                t2v[i] = b2 ? l1v : c2v; t2i[i] = b2 ? l1i : c2i;
            }
        }
        if (l == 0) {
#pragma unroll
            for (int i = 0; i < 4; i++) {
                int v = vbase + quad * 4 + i;
                int o = (v * NSEG + seg) * 2;
                pval[o] = t1v[i];     pidx[o] = t1i[i];
                pval[o + 1] = t2v[i]; pidx[o + 1] = t2i[i];
            }
        }
    }
}

// ---------------- stage 2: merge segment partials, emit top_vals/top_idx ----------------

__global__ __launch_bounds__(256) void k_top2_merge(const float* __restrict__ pval, const int* __restrict__ pidx,
                                                    const int* __restrict__ nact,
                                                    float* __restrict__ out, int* __restrict__ tidx) {
    int v = blockIdx.x * 256 + threadIdx.x;
    if (v >= NN) return;
    int na = nact[v >> 6];
    float v1 = NEGV, v2 = NEGV; int i1 = 0x7fffffff, i2 = 0x7fffffff;
    if (na == 0) { i1 = 0; i2 = 1; }
    for (int t = 0; t < na * 2; t++) {
        float val = pval[v * (NSEG * 2) + t]; int idx = pidx[v * (NSEG * 2) + t];
        if (val > v1 || (val == v1 && idx < i1)) { v2 = v1; i2 = i1; v1 = val; i1 = idx; }
        else if (val > v2 || (val == v2 && idx < i2)) { v2 = val; i2 = idx; }
    }
    out[v * 2 + 0] = v1; out[v * 2 + 1] = v2;                    // top_vals
    out[2 * NN * 2 + v * 2 + 0] = (float)i1;                     // top_idx
    out[2 * NN * 2 + v * 2 + 1] = (float)i2;
    tidx[v * 2] = i1; tidx[v * 2 + 1] = i2;
}

// ---------------- inversion-bit epilogue: logit = inv2 . relu(P[u]+Q[v]+cz) + b ----------------

__global__ __launch_bounds__(256) void k_inv(const float* __restrict__ P, const float* __restrict__ Q,
                                             const float* __restrict__ cz, const float* __restrict__ w2,
                                             const float* __restrict__ b2, const int* __restrict__ tidx,
                                             float* __restrict__ out) {
    int gid = blockIdx.x * 256 + threadIdx.x;
    int wid = gid >> 6;
    int lane = gid & 63;
    if (wid >= NN * 2) return;
    int v = wid >> 1;
    int u = tidx[wid]; if (u > NN - 1) u = NN - 1; if (u < 0) u = 0;
    float h0 = fmaxf(P[u * HH + lane] + Q[v * HH + lane] + cz[lane], 0.f);
    float h1 = fmaxf(P[u * HH + 64 + lane] + Q[v * HH + 64 + lane] + cz[64 + lane], 0.f);
    float p = h0 * w2[lane] + h1 * w2[64 + lane];
    for (int off = 32; off >= 1; off >>= 1) p += __shfl_down(p, off, 64);
    if (lane == 0) {
        float logit = p + b2[0];
        out[NN * 2 + wid] = logit;                               // inv_logit
        out[3 * NN * 2 + wid] = (logit > 0.f) ? 1.f : 0.f;       // inv_bit
    }
}

// ---------------- launch ----------------

extern "C" void kernel_launch(void* const* d_in, const int* in_sizes, int n_in,
                              void* d_out, int out_size, void* d_ws, size_t ws_size,
                              hipStream_t stream) {
    const float* x       = (const float*)d_in[0];
    const float* z       = (const float*)d_in[1];
    const int*   eidx    = (const int*)d_in[2];
    const int*   depth   = (const int*)d_in[3];
    const float* conv1_w = (const float*)d_in[4];
    const float* conv1_b = (const float*)d_in[5];
    const float* conv2_w = (const float*)d_in[6];
    const float* conv2_b = (const float*)d_in[7];
    const float* np1_w   = (const float*)d_in[8];
    const float* np1_b   = (const float*)d_in[9];
    const float* np2_w   = (const float*)d_in[10];
    const float* np2_b   = (const float*)d_in[11];
    const float* src_w   = (const float*)d_in[12];
    const float* tgt_w   = (const float*)d_in[13];
    const float* inv1_w  = (const float*)d_in[14];
    const float* inv1_b  = (const float*)d_in[15];
    const float* inv2_w  = (const float*)d_in[16];
    const float* inv2_b  = (const float*)d_in[17];
    float* out = (float*)d_out;
    float* wsf = (float*)d_ws;

    const int NH = NN * HH;   // 1,048,576
    // Region map (floats):
    //   [0,NH)        h3
    //   [NH,4NH)      HtP (3NH shorts) + HsP (3NH shorts) during stage1;
    //                 earlier: A=[NH,2NH) B=[2NH,3NH) GCN temps; later: P=[NH,2NH) Q=[2NH,3NH)
    //   [4NH,5NH)     t (np1 out); later pval/pidx
    //   [5NH,...)     T, c1, cz, rsq, dinv, ints
    float* h3 = wsf;
    float* A  = wsf + (size_t)NH;
    float* B  = wsf + 2 * (size_t)NH;
    float* C  = wsf + 4 * (size_t)NH;
    unsigned short* HtP = (unsigned short*)(wsf + (size_t)NH);
    unsigned short* HsP = HtP + 3 * (size_t)NH;
    float* P = wsf + (size_t)NH;         // after stage1 (planes dead)
    float* Q = wsf + 2 * (size_t)NH;
    float* pval = wsf + 4 * (size_t)NH;  // NN*NSEG*2 = 524288 floats
    int*   pidx = (int*)(pval + NN * NSEG * 2);
    float* T  = wsf + 5 * (size_t)NH;
    float* c1 = T + 7 * 16384;
    float* cz = c1 + 128;
    float* rsq  = cz + 128;
    float* dinv = rsq + NN;
    int* degi   = (int*)(dinv + NN);
    int* rowptr = degi + NN;             // NN+1
    int* cursor = rowptr + NN + 1;
    int* cnt    = cursor + NN;
    int* nact   = cnt + NN;              // 128
    int* ntiles = nact + 128;
    int* tctr   = ntiles + 1;
    int* tidx   = tctr + 1;              // 2*NN
    int* tlist  = tidx + 2 * NN;         // <= 4096
    int* ecsr   = tlist + 4096;          // EE

    const int* esrc = eidx;
    const int* edst = eidx + EE;

    hipMemsetAsync(degi, 0, NN * sizeof(int), stream);
    hipMemsetAsync(cursor, 0, NN * sizeof(int), stream);
    hipMemsetAsync(tctr, 0, sizeof(int), stream);
    k_prep<<<dim3(64, 8), 256, 0, stream>>>(conv2_w, np1_w, np2_w, src_w, tgt_w, inv1_w,
                                            np1_b, inv1_b, z, T, c1, cz);
    k_deg<<<EE / 256, 256, 0, stream>>>(edst, degi);
    k_rsq<<<NN / 256, 256, 0, stream>>>(degi, dinv, rsq);
    k_scan<<<1, 1024, 0, stream>>>(degi, rowptr);
    k_fill<<<EE / 256, 256, 0, stream>>>(esrc, edst, rowptr, cursor, ecsr);
    k_xw1<<<NH / 256, 256, 0, stream>>>(x, conv1_w, A);
    k_gather<<<NN * 64 / 256, 256, 0, stream>>>(rowptr, ecsr, rsq, dinv, A, conv1_b, B);   // h1
    k_gemm128<<<256, 256, 0, stream>>>(B, T + 0 * 16384, nullptr, A, 0);                   // xw2
    k_gather<<<NN * 64 / 256, 256, 0, stream>>>(rowptr, ecsr, rsq, dinv, A, conv2_b, B);   // h2
    k_gemm128<<<256, 256, 0, stream>>>(B, T + 1 * 16384, c1, C, 1);        // t = relu(h2@np1h^T + c1)
    k_gemm128<<<256, 256, 0, stream>>>(C, T + 2 * 16384, np2_b, h3, 0);    // h3
    k_gemmHtHs<<<dim3(256, 2), 256, 0, stream>>>(h3, T, HtP, HsP);
    k_cnt_valid<<<NN / 256, 256, 0, stream>>>(depth, x, cnt, out);
    k_tiles<<<1, 128, 0, stream>>>(cnt, nact, tlist, ntiles);
    k_top2_stage1<<<768, 256, 0, stream>>>(HtP, HsP, cnt, tlist, ntiles, tctr, pval, pidx);
    k_top2_merge<<<NN / 256, 256, 0, stream>>>(pval, pidx, nact, out, tidx);
    k_gemm128<<<256, 256, 0, stream>>>(h3, T + 5 * 16384, nullptr, P, 0);  // P = h3@inv1a^T
    k_gemm128<<<256, 256, 0, stream>>>(h3, T + 6 * 16384, nullptr, Q, 0);  // Q = h3@inv1b^T
    k_inv<<<(NN * 2 * 64) / 256, 256, 0, stream>>>(P, Q, cz, inv2_w, inv2_b, tidx, out);
}

// Round 7
// 382.860 us; speedup vs baseline: 1.1056x; 1.0228x over previous
//
#include <hip/hip_runtime.h>

#define NN 8192
#define EE 131072
#define HH 128
#define NEGV -1.0e30f
#define SEG 128
#define NSEG (NN / SEG)   // 64
#define VT 128            // v-rows per stage1 block (4 waves x 32)

typedef __attribute__((ext_vector_type(8))) short bf16x8;
typedef __attribute__((ext_vector_type(4))) float f32x4;

__device__ __forceinline__ unsigned short f2bf(float f) {
    unsigned int u = __float_as_uint(f);
    unsigned int r = u + 0x7fffu + ((u >> 16) & 1u);
    return (unsigned short)(r >> 16);
}
__device__ __forceinline__ float bf2f(unsigned short b) {
    return __uint_as_float((unsigned int)b << 16);
}

// ---------------- degree (int) ----------------

__global__ __launch_bounds__(256) void k_deg(const int* __restrict__ dst, int* __restrict__ degi) {
    int t = blockIdx.x * 256 + threadIdx.x;
    if (t < EE) atomicAdd(&degi[dst[t]], 1);
}

// exclusive scan of degi[NN] -> rowptr[NN+1]; also dinv/rsq. One block of 1024, 8/thread.
__global__ __launch_bounds__(1024) void k_scan(const int* __restrict__ degi, int* __restrict__ rowptr,
                                               float* __restrict__ dinv, float* __restrict__ rsq) {
    __shared__ int ls[1024];
    int tid = threadIdx.x;
    int base = tid * 8;
    int loc[8]; int s = 0;
#pragma unroll
    for (int i = 0; i < 8; i++) {
        int dg = degi[base + i];
        loc[i] = s; s += dg;
        double d = (double)(dg + 1);
        dinv[base + i] = (float)(1.0 / d);
        rsq[base + i] = (float)(1.0 / sqrt(d));
    }
    ls[tid] = s; __syncthreads();
    int tot = s;
    for (int d = 1; d < 1024; d <<= 1) {
        int v = (tid >= d) ? ls[tid - d] : 0;
        __syncthreads();
        ls[tid] += v;
        __syncthreads();
    }
    int pre = ls[tid] - tot;
#pragma unroll
    for (int i = 0; i < 8; i++) rowptr[base + i] = pre + loc[i];
    if (tid == 1023) rowptr[NN] = pre + tot;
}

__global__ __launch_bounds__(256) void k_fill(const int* __restrict__ src, const int* __restrict__ dst,
                                              const int* __restrict__ rowptr, int* __restrict__ cursor,
                                              int* __restrict__ ecsr) {
    int t = blockIdx.x * 256 + threadIdx.x;
    if (t < EE) {
        int d = dst[t];
        int pos = atomicAdd(&cursor[d], 1);
        ecsr[rowptr[d] + pos] = src[t];
    }
}

// ---------------- GCN layer 1: gather with on-the-fly x@W1^T (IN_DIM=2) ----------------

__global__ __launch_bounds__(256) void k_gather1(const int* __restrict__ rowptr, const int* __restrict__ ecsr,
                                                 const float* __restrict__ rsq, const float* __restrict__ dinv,
                                                 const float* __restrict__ x, const float* __restrict__ w,
                                                 const float* __restrict__ bias, float* __restrict__ out) {
    int g = blockIdx.x * 256 + threadIdx.x;
    int d = g >> 6, lane = g & 63;
    if (d >= NN) return;
    float w0a = w[lane * 2], w1a = w[lane * 2 + 1];
    float w0b = w[(lane + 64) * 2], w1b = w[(lane + 64) * 2 + 1];
    int s0 = rowptr[d], s1 = rowptr[d + 1];
    float rd = rsq[d];
    float a0 = 0.f, a1 = 0.f;
    for (int sl = s0; sl < s1; sl++) {
        int s = ecsr[sl];
        float x0 = x[s * 2], x1 = x[s * 2 + 1];
        float f = rsq[s] * rd;
        a0 = fmaf(f, x0 * w0a + x1 * w1a, a0);
        a1 = fmaf(f, x0 * w0b + x1 * w1b, a1);
    }
    float x0d = x[d * 2], x1d = x[d * 2 + 1], di = dinv[d];
    a0 = fmaf(x0d * w0a + x1d * w1a, di, a0) + bias[lane];
    a1 = fmaf(x0d * w0b + x1d * w1b, di, a1) + bias[64 + lane];
    out[d * HH + lane] = fmaxf(a0, 0.f);
    out[d * HH + 64 + lane] = fmaxf(a1, 0.f);
}

// ---------------- GCN layer 2: gather over precomputed xw rows ----------------

__global__ __launch_bounds__(256) void k_gather2(const int* __restrict__ rowptr, const int* __restrict__ ecsr,
                                                 const float* __restrict__ rsq, const float* __restrict__ dinv,
                                                 const float* __restrict__ xw, const float* __restrict__ bias,
                                                 float* __restrict__ out) {
    int g = blockIdx.x * 256 + threadIdx.x;
    int d = g >> 6, lane = g & 63;
    if (d >= NN) return;
    int s0 = rowptr[d], s1 = rowptr[d + 1];
    float rd = rsq[d];
    float a0 = 0.f, a1 = 0.f;
    for (int sl = s0; sl < s1; sl++) {
        int s = ecsr[sl];                       // wave-uniform scalar load
        float f = rsq[s] * rd;
        a0 = fmaf(f, xw[s * HH + lane], a0);    // coalesced 256B row segment
        a1 = fmaf(f, xw[s * HH + 64 + lane], a1);
    }
    float di = dinv[d];
    a0 = fmaf(xw[d * HH + lane], di, a0) + bias[lane];
    a1 = fmaf(xw[d * HH + 64 + lane], di, a1) + bias[64 + lane];
    out[d * HH + lane] = fmaxf(a0, 0.f);
    out[d * HH + 64 + lane] = fmaxf(a1, 0.f);
}

// ---------------- weight prep: transposes + folded-z biases ----------------
// T: 0 conv2, 1 np1(h-part), 2 np2, 3 src, 4 tgt, 5 inv1(h_u), 6 inv1(h_v)

__global__ __launch_bounds__(256) void k_prep(const float* __restrict__ conv2_w, const float* __restrict__ np1_w,
                                              const float* __restrict__ np2_w, const float* __restrict__ src_w,
                                              const float* __restrict__ tgt_w, const float* __restrict__ inv1_w,
                                              const float* __restrict__ np1_b, const float* __restrict__ inv1_b,
                                              const float* __restrict__ z, float* __restrict__ T,
                                              float* __restrict__ c1, float* __restrict__ cz) {
    int y = blockIdx.y;
    if (y < 7) {
        int t = blockIdx.x * 256 + threadIdx.x;
        int j = t >> 7, k = t & 127;
        const float* W; int stride, off;
        switch (y) {
            case 0:  W = conv2_w; stride = 128; off = 0;   break;
            case 1:  W = np1_w;   stride = 256; off = 0;   break;
            case 2:  W = np2_w;   stride = 128; off = 0;   break;
            case 3:  W = src_w;   stride = 128; off = 0;   break;
            case 4:  W = tgt_w;   stride = 128; off = 0;   break;
            case 5:  W = inv1_w;  stride = 384; off = 0;   break;
            default: W = inv1_w;  stride = 384; off = 128; break;
        }
        T[y * 16384 + k * 128 + j] = W[j * stride + off + k];
    } else if (blockIdx.x == 0) {
        int tid = threadIdx.x;
        if (tid < 128) {
            float s = np1_b[tid];
            for (int k = 0; k < 128; k++) s += z[k] * np1_w[tid * 256 + 128 + k];
            c1[tid] = s;
        } else {
            int j = tid - 128;
            float s = inv1_b[j];
            for (int k = 0; k < 128; k++) s += z[k] * inv1_w[j * 384 + 256 + k];
            cz[j] = s;
        }
    }
}

// ---------------- generic [8192x128] @ WT[128x128] (+bias)(+relu) ----------------

__global__ __launch_bounds__(256) void k_gemm128(const float* __restrict__ A, const float* __restrict__ WT,
                                                 const float* __restrict__ bias, float* __restrict__ out,
                                                 int relu) {
    __shared__ float As[32][33];
    __shared__ float Bs[32][128];
    int tid = threadIdx.x;
    int tx = tid & 31, ty = tid >> 5;
    int row0 = blockIdx.x * 32;
    float acc[4][4] = {};
    for (int k0 = 0; k0 < 128; k0 += 32) {
        {
            int r = tid >> 3, k = (tid & 7) << 2;
            float4 v = *(const float4*)&A[(row0 + r) * HH + k0 + k];
            As[r][k] = v.x; As[r][k + 1] = v.y; As[r][k + 2] = v.z; As[r][k + 3] = v.w;
        }
#pragma unroll
        for (int i = 0; i < 4; i++) {
            int kk = (tid >> 5) + i * 8;
            int c = (tid & 31) << 2;
            *(float4*)&Bs[kk][c] = *(const float4*)&WT[(k0 + kk) * HH + c];
        }
        __syncthreads();
#pragma unroll 8
        for (int kk = 0; kk < 32; kk++) {
            float a0 = As[ty * 4 + 0][kk], a1 = As[ty * 4 + 1][kk];
            float a2 = As[ty * 4 + 2][kk], a3 = As[ty * 4 + 3][kk];
            float4 b = *(const float4*)&Bs[kk][tx * 4];
            acc[0][0] = fmaf(a0, b.x, acc[0][0]); acc[0][1] = fmaf(a0, b.y, acc[0][1]);
            acc[0][2] = fmaf(a0, b.z, acc[0][2]); acc[0][3] = fmaf(a0, b.w, acc[0][3]);
            acc[1][0] = fmaf(a1, b.x, acc[1][0]); acc[1][1] = fmaf(a1, b.y, acc[1][1]);
            acc[1][2] = fmaf(a1, b.z, acc[1][2]); acc[1][3] = fmaf(a1, b.w, acc[1][3]);
            acc[2][0] = fmaf(a2, b.x, acc[2][0]); acc[2][1] = fmaf(a2, b.y, acc[2][1]);
            acc[2][2] = fmaf(a2, b.z, acc[2][2]); acc[2][3] = fmaf(a2, b.w, acc[2][3]);
            acc[3][0] = fmaf(a3, b.x, acc[3][0]); acc[3][1] = fmaf(a3, b.y, acc[3][1]);
            acc[3][2] = fmaf(a3, b.z, acc[3][2]); acc[3][3] = fmaf(a3, b.w, acc[3][3]);
        }
        __syncthreads();
    }
#pragma unroll
    for (int i = 0; i < 4; i++) {
        float4 v = make_float4(acc[i][0], acc[i][1], acc[i][2], acc[i][3]);
        if (bias) {
            v.x += bias[tx * 4]; v.y += bias[tx * 4 + 1];
            v.z += bias[tx * 4 + 2]; v.w += bias[tx * 4 + 3];
        }
        if (relu) {
            v.x = fmaxf(v.x, 0.f); v.y = fmaxf(v.y, 0.f);
            v.z = fmaxf(v.z, 0.f); v.w = fmaxf(v.w, 0.f);
        }
        *(float4*)&out[(row0 + ty * 4 + i) * HH + tx * 4] = v;
    }
}

// ---------------- fused MLP: h2 -> t -> h3 (LDS-resident) -> Ht/Hs split-bf16 planes ----------------
// 4 chained GEMMs per 32-row block; h3 also written to global (for P/Q later).
// Plane layout: PP[(chunk*NN + row)*96 + plane*32 + colInChunk].

__global__ __launch_bounds__(256) void k_mlp(const float* __restrict__ h2g, const float* __restrict__ T,
                                             const float* __restrict__ c1, const float* __restrict__ np2_b,
                                             float* __restrict__ h3g,
                                             unsigned short* __restrict__ HtP, unsigned short* __restrict__ HsP) {
    __shared__ float bufA[32][132];
    __shared__ float bufB[32][132];
    __shared__ float Bs[32][128];
    int tid = threadIdx.x;
    int tx = tid & 31, ty = tid >> 5;
    int row0 = blockIdx.x * 32;
    // load h2 tile into bufA
#pragma unroll
    for (int p = 0; p < 4; p++) {
        int q = p * 256 + tid;
        int r = q >> 5, c4 = (q & 31) * 4;
        *(float4*)&bufA[r][c4] = *(const float4*)&h2g[(size_t)(row0 + r) * HH + c4];
    }
    __syncthreads();
    for (int g = 0; g < 4; g++) {
        const float* WT;
        switch (g) {
            case 0:  WT = T + 1 * 16384; break;   // np1 (h-part)
            case 1:  WT = T + 2 * 16384; break;   // np2
            case 2:  WT = T + 4 * 16384; break;   // tgt -> Ht
            default: WT = T + 3 * 16384; break;   // src -> Hs
        }
        float (*src)[132] = (g == 1) ? bufB : bufA;
        float acc[4][4] = {};
        for (int k0 = 0; k0 < 128; k0 += 32) {
#pragma unroll
            for (int i = 0; i < 4; i++) {
                int kk = (tid >> 5) + i * 8;
                int c = (tid & 31) << 2;
                *(float4*)&Bs[kk][c] = *(const float4*)&WT[(k0 + kk) * HH + c];
            }
            __syncthreads();
#pragma unroll 8
            for (int kk = 0; kk < 32; kk++) {
                float a0 = src[ty * 4 + 0][k0 + kk], a1 = src[ty * 4 + 1][k0 + kk];
                float a2 = src[ty * 4 + 2][k0 + kk], a3 = src[ty * 4 + 3][k0 + kk];
                float4 b = *(const float4*)&Bs[kk][tx * 4];
                acc[0][0] = fmaf(a0, b.x, acc[0][0]); acc[0][1] = fmaf(a0, b.y, acc[0][1]);
                acc[0][2] = fmaf(a0, b.z, acc[0][2]); acc[0][3] = fmaf(a0, b.w, acc[0][3]);
                acc[1][0] = fmaf(a1, b.x, acc[1][0]); acc[1][1] = fmaf(a1, b.y, acc[1][1]);
                acc[1][2] = fmaf(a1, b.z, acc[1][2]); acc[1][3] = fmaf(a1, b.w, acc[1][3]);
                acc[2][0] = fmaf(a2, b.x, acc[2][0]); acc[2][1] = fmaf(a2, b.y, acc[2][1]);
                acc[2][2] = fmaf(a2, b.z, acc[2][2]); acc[2][3] = fmaf(a2, b.w, acc[2][3]);
                acc[3][0] = fmaf(a3, b.x, acc[3][0]); acc[3][1] = fmaf(a3, b.y, acc[3][1]);
                acc[3][2] = fmaf(a3, b.z, acc[3][2]); acc[3][3] = fmaf(a3, b.w, acc[3][3]);
            }
            __syncthreads();
        }
        if (g == 0) {          // t = relu(. + c1) -> bufB
#pragma unroll
            for (int i = 0; i < 4; i++)
#pragma unroll
                for (int jj = 0; jj < 4; jj++)
                    bufB[ty * 4 + i][tx * 4 + jj] = fmaxf(acc[i][jj] + c1[tx * 4 + jj], 0.f);
        } else if (g == 1) {   // h3 = . + np2_b -> bufA + global
#pragma unroll
            for (int i = 0; i < 4; i++) {
                float4 v;
                v.x = acc[i][0] + np2_b[tx * 4 + 0];
                v.y = acc[i][1] + np2_b[tx * 4 + 1];
                v.z = acc[i][2] + np2_b[tx * 4 + 2];
                v.w = acc[i][3] + np2_b[tx * 4 + 3];
                bufA[ty * 4 + i][tx * 4 + 0] = v.x; bufA[ty * 4 + i][tx * 4 + 1] = v.y;
                bufA[ty * 4 + i][tx * 4 + 2] = v.z; bufA[ty * 4 + i][tx * 4 + 3] = v.w;
                *(float4*)&h3g[(size_t)(row0 + ty * 4 + i) * HH + tx * 4] = v;
            }
        } else {               // split-bf16 3-plane emission
            unsigned short* PP = (g == 2) ? HtP : HsP;
            int chunk = tx >> 3;
            int cic = (tx * 4) & 31;
#pragma unroll
            for (int i = 0; i < 4; i++) {
                int row = row0 + ty * 4 + i;
                size_t off = ((size_t)(chunk * NN + row)) * 96 + cic;
                unsigned short h[4], m[4], lo[4];
#pragma unroll
                for (int jj = 0; jj < 4; jj++) {
                    float val = acc[i][jj];
                    unsigned short hb = f2bf(val);
                    float r1 = val - bf2f(hb);
                    unsigned short mb = f2bf(r1);
                    float r2 = r1 - bf2f(mb);
                    h[jj] = hb; m[jj] = mb; lo[jj] = f2bf(r2);
                }
                *(uint2*)&PP[off] = make_uint2((unsigned)h[0] | ((unsigned)h[1] << 16),
                                               (unsigned)h[2] | ((unsigned)h[3] << 16));
                *(uint2*)&PP[off + 32] = make_uint2((unsigned)m[0] | ((unsigned)m[1] << 16),
                                                    (unsigned)m[2] | ((unsigned)m[3] << 16));
                *(uint2*)&PP[off + 64] = make_uint2((unsigned)lo[0] | ((unsigned)lo[1] << 16),
                                                    (unsigned)lo[2] | ((unsigned)lo[3] << 16));
            }
        }
    }
}

// ---------------- candidate counts + valid flags ----------------

__global__ __launch_bounds__(256) void k_cnt_valid(const int* __restrict__ depth, const float* __restrict__ x,
                                                   int* __restrict__ cnt, float* __restrict__ out) {
    int v = blockIdx.x * 256 + threadIdx.x;
    if (v >= NN) return;
    int limit = depth[v] + 1;   // depth[v]-1+DEPTH_PERTURB
    int lo = 0, hi = NN;
    while (lo < hi) { int mid = (lo + hi) >> 1; if (depth[mid] <= limit) lo = mid + 1; else hi = mid; }
    cnt[v] = lo;
    int type = (int)(x[v * 2] + 0.5f);
    bool tv = (depth[v] >= 1) && (type != 0);
    out[4 * NN * 2 + v * 2 + 0] = (tv && lo >= 1) ? 1.0f : 0.0f;
    out[4 * NN * 2 + v * 2 + 1] = (tv && type == 2 && lo >= 2) ? 1.0f : 0.0f;
}

// ---------------- active tile list (128-row v-blocks -> 64 entries, one wave) ----------------

__global__ __launch_bounds__(64) void k_tiles(const int* __restrict__ cnt, int* __restrict__ nact,
                                              int* __restrict__ tlist, int* __restrict__ ntiles) {
    int lane = threadIdx.x;   // 0..63, one per 128-row v-block
    int cmax = cnt[lane * VT + VT - 1];
    int n = (cmax + SEG - 1) / SEG;   // <= 64
    nact[lane] = n;
    int x = n;
    for (int off = 1; off < 64; off <<= 1) {
        int y = __shfl_up(x, off, 64);
        if (lane >= off) x += y;
    }
    int base = x - n;
    for (int s = 0; s < n; s++) tlist[base + s] = (lane << 8) | s;
    if (lane == 63) *ntiles = x;
}

// ---------------- fused masked GEMM + top-2 (stage 1, 3-plane split-bf16 MFMA, R=32) ----------------
// Persistent blocks; 4 waves/block; each wave holds TWO 16-row A-sets (96 VGPRs) so every
// B fragment load feeds 2 MFMAs — halves L1 traffic vs R=16 (the measured 15.5% MfmaUtil wall).
// launch_bounds(256,2): 256-VGPR cap, no rematerialization. B addresses identical across waves.

__global__ __launch_bounds__(256, 2) void k_top2_stage1(
    const unsigned short* __restrict__ HtP, const unsigned short* __restrict__ HsP,
    const int* __restrict__ cnt, const int* __restrict__ tlist,
    const int* __restrict__ ntiles, int* __restrict__ tctr,
    float* __restrict__ pval, int* __restrict__ pidx) {
    __shared__ int tsh;
    int tid = threadIdx.x;
    int wave = tid >> 6, lane = tid & 63;
    int l = lane & 15, quad = lane >> 4;
    int nt = *ntiles;
    for (;;) {
        if (tid == 0) tsh = atomicAdd(tctr, 1);
        __syncthreads();
        int t = tsh;
        __syncthreads();
        if (t >= nt) return;
        int code = tlist[t];
        int v0 = (code >> 8) * VT;
        int seg = code & 255;
        int ub0 = seg * SEG;
        int vbase = v0 + wave * 32;
        // A fragments: [set][chunk][hi|mid|lo]; A[m=lane&15][k=quad*8+j]
        bf16x8 afr[2][4][3];
#pragma unroll
        for (int s = 0; s < 2; s++)
#pragma unroll
            for (int c = 0; c < 4; c++) {
                size_t ao = ((size_t)(c * NN + vbase + s * 16 + l)) * 96 + quad * 8;
                afr[s][c][0] = *(const bf16x8*)&HtP[ao];
                afr[s][c][1] = *(const bf16x8*)&HtP[ao + 32];
                afr[s][c][2] = *(const bf16x8*)&HtP[ao + 64];
            }
        // C/D layout (16x16x32): col(u)=lane&15, row(v)=quad*4+reg (per set)
        int creg[8];
#pragma unroll
        for (int i = 0; i < 8; i++)
            creg[i] = cnt[vbase + (i >> 2) * 16 + quad * 4 + (i & 3)];
        float t1v[8], t2v[8]; int t1i[8], t2i[8];
#pragma unroll
        for (int i = 0; i < 8; i++) { t1v[i] = NEGV; t2v[i] = NEGV; t1i[i] = 0x7fffffff; t2i[i] = 0x7fffffff; }
        int cmax = cnt[v0 + VT - 1];
        int uend = ub0 + SEG; if (uend > cmax) uend = cmax;
        for (int u0 = ub0; u0 < uend; u0 += 16) {
            int u = u0 + l;   // < 8192 always (u0 multiple of 16, <= 8176)
            f32x4 acc0 = {0.f, 0.f, 0.f, 0.f}, acc1 = {0.f, 0.f, 0.f, 0.f};
#pragma unroll
            for (int c = 0; c < 4; c++) {
                size_t bo = ((size_t)(c * NN + u)) * 96 + quad * 8;
                bf16x8 bh = *(const bf16x8*)&HsP[bo];
                bf16x8 bm = *(const bf16x8*)&HsP[bo + 32];
                bf16x8 bl = *(const bf16x8*)&HsP[bo + 64];
                acc0 = __builtin_amdgcn_mfma_f32_16x16x32_bf16(afr[0][c][0], bh, acc0, 0, 0, 0);
                acc1 = __builtin_amdgcn_mfma_f32_16x16x32_bf16(afr[1][c][0], bh, acc1, 0, 0, 0);
                acc0 = __builtin_amdgcn_mfma_f32_16x16x32_bf16(afr[0][c][0], bm, acc0, 0, 0, 0);
                acc1 = __builtin_amdgcn_mfma_f32_16x16x32_bf16(afr[1][c][0], bm, acc1, 0, 0, 0);
                acc0 = __builtin_amdgcn_mfma_f32_16x16x32_bf16(afr[0][c][1], bh, acc0, 0, 0, 0);
                acc1 = __builtin_amdgcn_mfma_f32_16x16x32_bf16(afr[1][c][1], bh, acc1, 0, 0, 0);
                acc0 = __builtin_amdgcn_mfma_f32_16x16x32_bf16(afr[0][c][0], bl, acc0, 0, 0, 0);
                acc1 = __builtin_amdgcn_mfma_f32_16x16x32_bf16(afr[1][c][0], bl, acc1, 0, 0, 0);
                acc0 = __builtin_amdgcn_mfma_f32_16x16x32_bf16(afr[0][c][2], bh, acc0, 0, 0, 0);
                acc1 = __builtin_amdgcn_mfma_f32_16x16x32_bf16(afr[1][c][2], bh, acc1, 0, 0, 0);
                acc0 = __builtin_amdgcn_mfma_f32_16x16x32_bf16(afr[0][c][1], bm, acc0, 0, 0, 0);
                acc1 = __builtin_amdgcn_mfma_f32_16x16x32_bf16(afr[1][c][1], bm, acc1, 0, 0, 0);
            }
#pragma unroll
            for (int i = 0; i < 8; i++) {
                float sv = (i < 4) ? acc0[i & 3] : acc1[i & 3];
                float val = (u < creg[i]) ? sv : NEGV;   // masked: NEG with real index
                if (val > t1v[i] || (val == t1v[i] && u < t1i[i])) {
                    t2v[i] = t1v[i]; t2i[i] = t1i[i]; t1v[i] = val; t1i[i] = u;
                } else if (val > t2v[i] || (val == t2v[i] && u < t2i[i])) {
                    t2v[i] = val; t2i[i] = u;
                }
            }
        }
        // merge top-2 across the 16 lanes of each quad group (disjoint u sets)
#pragma unroll
        for (int m = 1; m <= 8; m <<= 1) {
#pragma unroll
            for (int i = 0; i < 8; i++) {
                float ov1 = __shfl_xor(t1v[i], m, 64);
                int   oi1 = __shfl_xor(t1i[i], m, 64);
                float ov2 = __shfl_xor(t2v[i], m, 64);
                int   oi2 = __shfl_xor(t2i[i], m, 64);
                bool b1 = (ov1 > t1v[i]) || (ov1 == t1v[i] && oi1 < t1i[i]);
                float w1v = b1 ? ov1 : t1v[i]; int w1i = b1 ? oi1 : t1i[i];
                float l1v = b1 ? t1v[i] : ov1; int l1i = b1 ? t1i[i] : oi1;
                float c2v = b1 ? ov2 : t2v[i]; int c2i = b1 ? oi2 : t2i[i];
                bool b2 = (l1v > c2v) || (l1v == c2v && l1i < c2i);
                t1v[i] = w1v; t1i[i] = w1i;
                t2v[i] = b2 ? l1v : c2v; t2i[i] = b2 ? l1i : c2i;
            }
        }
        if (l == 0) {
#pragma unroll
            for (int i = 0; i < 8; i++) {
                int v = vbase + (i >> 2) * 16 + quad * 4 + (i & 3);
                int o = (v * NSEG + seg) * 2;
                pval[o] = t1v[i];     pidx[o] = t1i[i];
                pval[o + 1] = t2v[i]; pidx[o + 1] = t2i[i];
            }
        }
    }
}

// ---------------- fused merge + inversion epilogue: one wave per v ----------------

__global__ __launch_bounds__(256) void k_merge_inv(const float* __restrict__ pval, const int* __restrict__ pidx,
                                                   const int* __restrict__ nact,
                                                   const float* __restrict__ P, const float* __restrict__ Q,
                                                   const float* __restrict__ cz, const float* __restrict__ w2,
                                                   const float* __restrict__ b2, float* __restrict__ out) {
    int gid = blockIdx.x * 256 + threadIdx.x;
    int v = gid >> 6, lane = gid & 63;
    if (v >= NN) return;
    int na = nact[v >> 7];
    float v1 = NEGV, v2 = NEGV; int i1 = 0x7fffffff, i2 = 0x7fffffff;
    if (lane < na) {
        int o = (v * NSEG + lane) * 2;
        v1 = pval[o];     i1 = pidx[o];
        v2 = pval[o + 1]; i2 = pidx[o + 1];
    }
#pragma unroll
    for (int m = 1; m <= 32; m <<= 1) {
        float ov1 = __shfl_xor(v1, m, 64);
        int   oi1 = __shfl_xor(i1, m, 64);
        float ov2 = __shfl_xor(v2, m, 64);
        int   oi2 = __shfl_xor(i2, m, 64);
        bool b1 = (ov1 > v1) || (ov1 == v1 && oi1 < i1);
        float w1v = b1 ? ov1 : v1; int w1i = b1 ? oi1 : i1;
        float l1v = b1 ? v1 : ov1; int l1i = b1 ? i1 : oi1;
        float c2v = b1 ? ov2 : v2; int c2i = b1 ? oi2 : i2;
        bool b2 = (l1v > c2v) || (l1v == c2v && l1i < c2i);
        v1 = w1v; i1 = w1i;
        v2 = b2 ? l1v : c2v; i2 = b2 ? l1i : c2i;
    }
    if (na == 0) { v1 = NEGV; v2 = NEGV; i1 = 0; i2 = 1; }
    int u1 = i1, u2 = i2;   // always in [0, NN) by construction
    float cza = cz[lane], czb = cz[64 + lane];
    float w2a = w2[lane], w2b = w2[64 + lane];
    float Qa = Q[(size_t)v * HH + lane], Qb = Q[(size_t)v * HH + 64 + lane];
    float p0 = fmaxf(P[(size_t)u1 * HH + lane] + Qa + cza, 0.f) * w2a +
               fmaxf(P[(size_t)u1 * HH + 64 + lane] + Qb + czb, 0.f) * w2b;
    float p1 = fmaxf(P[(size_t)u2 * HH + lane] + Qa + cza, 0.f) * w2a +
               fmaxf(P[(size_t)u2 * HH + 64 + lane] + Qb + czb, 0.f) * w2b;
#pragma unroll
    for (int off = 32; off >= 1; off >>= 1) {
        p0 += __shfl_down(p0, off, 64);
        p1 += __shfl_down(p1, off, 64);
    }
    if (lane == 0) {
        float bb = b2[0];
        float l0 = p0 + bb, l1 = p1 + bb;
        out[v * 2 + 0] = v1; out[v * 2 + 1] = v2;                 // top_vals
        out[NN * 2 + v * 2 + 0] = l0;                             // inv_logit
        out[NN * 2 + v * 2 + 1] = l1;
        out[2 * NN * 2 + v * 2 + 0] = (float)i1;                  // top_idx
        out[2 * NN * 2 + v * 2 + 1] = (float)i2;
        out[3 * NN * 2 + v * 2 + 0] = (l0 > 0.f) ? 1.f : 0.f;     // inv_bit
        out[3 * NN * 2 + v * 2 + 1] = (l1 > 0.f) ? 1.f : 0.f;
    }
}

// ---------------- launch ----------------

extern "C" void kernel_launch(void* const* d_in, const int* in_sizes, int n_in,
                              void* d_out, int out_size, void* d_ws, size_t ws_size,
                              hipStream_t stream) {
    const float* x       = (const float*)d_in[0];
    const float* z       = (const float*)d_in[1];
    const int*   eidx    = (const int*)d_in[2];
    const int*   depth   = (const int*)d_in[3];
    const float* conv1_w = (const float*)d_in[4];
    const float* conv1_b = (const float*)d_in[5];
    const float* conv2_w = (const float*)d_in[6];
    const float* conv2_b = (const float*)d_in[7];
    const float* np1_w   = (const float*)d_in[8];
    const float* np1_b   = (const float*)d_in[9];
    const float* np2_w   = (const float*)d_in[10];
    const float* np2_b   = (const float*)d_in[11];
    const float* src_w   = (const float*)d_in[12];
    const float* tgt_w   = (const float*)d_in[13];
    const float* inv1_w  = (const float*)d_in[14];
    const float* inv1_b  = (const float*)d_in[15];
    const float* inv2_w  = (const float*)d_in[16];
    const float* inv2_b  = (const float*)d_in[17];
    float* out = (float*)d_out;
    float* wsf = (float*)d_ws;

    const int NH = NN * HH;   // 1,048,576 floats = 4 MB
    // Region map (NH-float units):
    //   [0,1):  h1 -> h2 -> h3 (in-place per 32-row block in k_mlp)
    //   [1,2):  xw2; dead after gather2 -> HtP starts here; after stage1 -> P
    //   [1,4):  HtP (3NH shorts = 1.5NH fl) + HsP (1.5NH fl) during stage1; later P=[1,2), Q=[2,3)
    //   [4,5):  pval (NN*64*2 = NH floats)
    //   [5,6):  pidx (NH ints)
    //   [6,..): T, c1, cz, rsq, dinv, ints, ecsr
    float* R0 = wsf;                          // h1/h2/h3
    float* R1 = wsf + (size_t)NH;             // xw2 / planes / P
    unsigned short* HtP = (unsigned short*)R1;
    unsigned short* HsP = HtP + 3 * (size_t)NH;
    float* P = wsf + (size_t)NH;
    float* Q = wsf + 2 * (size_t)NH;
    float* pval = wsf + 4 * (size_t)NH;
    int*   pidx = (int*)(wsf + 5 * (size_t)NH);
    float* T  = wsf + 6 * (size_t)NH;
    float* c1 = T + 7 * 16384;
    float* cz = c1 + 128;
    float* rsq  = cz + 128;
    float* dinv = rsq + NN;
    int* degi   = (int*)(dinv + NN);
    int* rowptr = degi + NN;             // NN+1
    int* cursor = rowptr + NN + 1;
    int* cnt    = cursor + NN;
    int* nact   = cnt + NN;              // 64
    int* ntiles = nact + 64;
    int* tctr   = ntiles + 1;
    int* tlist  = tctr + 1;              // <= 4096
    int* ecsr   = tlist + 4096;          // EE

    const int* esrc = eidx;
    const int* edst = eidx + EE;

    hipMemsetAsync(degi, 0, NN * sizeof(int), stream);
    hipMemsetAsync(cursor, 0, NN * sizeof(int), stream);
    hipMemsetAsync(tctr, 0, sizeof(int), stream);
    k_prep<<<dim3(64, 8), 256, 0, stream>>>(conv2_w, np1_w, np2_w, src_w, tgt_w, inv1_w,
                                            np1_b, inv1_b, z, T, c1, cz);
    k_deg<<<EE / 256, 256, 0, stream>>>(edst, degi);
    k_scan<<<1, 1024, 0, stream>>>(degi, rowptr, dinv, rsq);
    k_fill<<<EE / 256, 256, 0, stream>>>(esrc, edst, rowptr, cursor, ecsr);
    k_gather1<<<NN * 64 / 256, 256, 0, stream>>>(rowptr, ecsr, rsq, dinv, x, conv1_w, conv1_b, R0);  // h1
    k_gemm128<<<256, 256, 0, stream>>>(R0, T + 0 * 16384, nullptr, R1, 0);                           // xw2
    k_gather2<<<NN * 64 / 256, 256, 0, stream>>>(rowptr, ecsr, rsq, dinv, R1, conv2_b, R0);          // h2
    k_mlp<<<256, 256, 0, stream>>>(R0, T, c1, np2_b, R0, HtP, HsP);        // h3 (in-place) + planes
    k_cnt_valid<<<NN / 256, 256, 0, stream>>>(depth, x, cnt, out);
    k_tiles<<<1, 64, 0, stream>>>(cnt, nact, tlist, ntiles);
    k_top2_stage1<<<512, 256, 0, stream>>>(HtP, HsP, cnt, tlist, ntiles, tctr, pval, pidx);
    k_gemm128<<<256, 256, 0, stream>>>(R0, T + 5 * 16384, nullptr, P, 0);  // P = h3@inv1a^T
    k_gemm128<<<256, 256, 0, stream>>>(R0, T + 6 * 16384, nullptr, Q, 0);  // Q = h3@inv1b^T
    k_merge_inv<<<NN / 4, 256, 0, stream>>>(pval, pidx, nact, P, Q, cz, inv2_w, inv2_b, out);
}

// Round 8
// 332.170 us; speedup vs baseline: 1.2743x; 1.1526x over previous
//
#include <hip/hip_runtime.h>

#define NN 8192
#define EE 131072
#define HH 128
#define NEGV -1.0e30f
#define SEG 128
#define NSEG (NN / SEG)   // 64
#define VT 128            // v-rows per stage1 block (4 waves x 32)

typedef __attribute__((ext_vector_type(8))) short bf16x8;
typedef __attribute__((ext_vector_type(4))) float f32x4;

__device__ __forceinline__ unsigned short f2bf(float f) {
    unsigned int u = __float_as_uint(f);
    unsigned int r = u + 0x7fffu + ((u >> 16) & 1u);
    return (unsigned short)(r >> 16);
}
__device__ __forceinline__ float bf2f(unsigned short b) {
    return __uint_as_float((unsigned int)b << 16);
}

// ---------------- degree (int) ----------------

__global__ __launch_bounds__(256) void k_deg(const int* __restrict__ dst, int* __restrict__ degi) {
    int t = blockIdx.x * 256 + threadIdx.x;
    if (t < EE) atomicAdd(&degi[dst[t]], 1);
}

// exclusive scan of degi[NN] -> rowptr[NN+1]; also dinv/rsq. One block of 1024, 8/thread.
__global__ __launch_bounds__(1024) void k_scan(const int* __restrict__ degi, int* __restrict__ rowptr,
                                               float* __restrict__ dinv, float* __restrict__ rsq) {
    __shared__ int ls[1024];
    int tid = threadIdx.x;
    int base = tid * 8;
    int loc[8]; int s = 0;
#pragma unroll
    for (int i = 0; i < 8; i++) {
        int dg = degi[base + i];
        loc[i] = s; s += dg;
        double d = (double)(dg + 1);
        dinv[base + i] = (float)(1.0 / d);
        rsq[base + i] = (float)(1.0 / sqrt(d));
    }
    ls[tid] = s; __syncthreads();
    int tot = s;
    for (int d = 1; d < 1024; d <<= 1) {
        int v = (tid >= d) ? ls[tid - d] : 0;
        __syncthreads();
        ls[tid] += v;
        __syncthreads();
    }
    int pre = ls[tid] - tot;
#pragma unroll
    for (int i = 0; i < 8; i++) rowptr[base + i] = pre + loc[i];
    if (tid == 1023) rowptr[NN] = pre + tot;
}

__global__ __launch_bounds__(256) void k_fill(const int* __restrict__ src, const int* __restrict__ dst,
                                              const int* __restrict__ rowptr, int* __restrict__ cursor,
                                              int* __restrict__ ecsr) {
    int t = blockIdx.x * 256 + threadIdx.x;
    if (t < EE) {
        int d = dst[t];
        int pos = atomicAdd(&cursor[d], 1);
        ecsr[rowptr[d] + pos] = src[t];
    }
}

// ---------------- GCN layer 1: gather with on-the-fly x@W1^T (IN_DIM=2) ----------------

__global__ __launch_bounds__(256) void k_gather1(const int* __restrict__ rowptr, const int* __restrict__ ecsr,
                                                 const float* __restrict__ rsq, const float* __restrict__ dinv,
                                                 const float* __restrict__ x, const float* __restrict__ w,
                                                 const float* __restrict__ bias, float* __restrict__ out) {
    int g = blockIdx.x * 256 + threadIdx.x;
    int d = g >> 6, lane = g & 63;
    if (d >= NN) return;
    float w0a = w[lane * 2], w1a = w[lane * 2 + 1];
    float w0b = w[(lane + 64) * 2], w1b = w[(lane + 64) * 2 + 1];
    int s0 = rowptr[d], s1 = rowptr[d + 1];
    float rd = rsq[d];
    float a0 = 0.f, a1 = 0.f;
    for (int sl = s0; sl < s1; sl++) {
        int s = ecsr[sl];
        float x0 = x[s * 2], x1 = x[s * 2 + 1];
        float f = rsq[s] * rd;
        a0 = fmaf(f, x0 * w0a + x1 * w1a, a0);
        a1 = fmaf(f, x0 * w0b + x1 * w1b, a1);
    }
    float x0d = x[d * 2], x1d = x[d * 2 + 1], di = dinv[d];
    a0 = fmaf(x0d * w0a + x1d * w1a, di, a0) + bias[lane];
    a1 = fmaf(x0d * w0b + x1d * w1b, di, a1) + bias[64 + lane];
    out[d * HH + lane] = fmaxf(a0, 0.f);
    out[d * HH + 64 + lane] = fmaxf(a1, 0.f);
}

// ---------------- GCN layer 2: gather over precomputed xw rows ----------------

__global__ __launch_bounds__(256) void k_gather2(const int* __restrict__ rowptr, const int* __restrict__ ecsr,
                                                 const float* __restrict__ rsq, const float* __restrict__ dinv,
                                                 const float* __restrict__ xw, const float* __restrict__ bias,
                                                 float* __restrict__ out) {
    int g = blockIdx.x * 256 + threadIdx.x;
    int d = g >> 6, lane = g & 63;
    if (d >= NN) return;
    int s0 = rowptr[d], s1 = rowptr[d + 1];
    float rd = rsq[d];
    float a0 = 0.f, a1 = 0.f;
    for (int sl = s0; sl < s1; sl++) {
        int s = ecsr[sl];                       // wave-uniform scalar load
        float f = rsq[s] * rd;
        a0 = fmaf(f, xw[s * HH + lane], a0);    // coalesced 256B row segment
        a1 = fmaf(f, xw[s * HH + 64 + lane], a1);
    }
    float di = dinv[d];
    a0 = fmaf(xw[d * HH + lane], di, a0) + bias[lane];
    a1 = fmaf(xw[d * HH + 64 + lane], di, a1) + bias[64 + lane];
    out[d * HH + lane] = fmaxf(a0, 0.f);
    out[d * HH + 64 + lane] = fmaxf(a1, 0.f);
}

// ---------------- weight prep: transposes + folded-z biases ----------------
// T: 0 conv2, 1 np1(h-part), 2 np2, 3 src, 4 tgt, 5 inv1(h_u), 6 inv1(h_v)

__global__ __launch_bounds__(256) void k_prep(const float* __restrict__ conv2_w, const float* __restrict__ np1_w,
                                              const float* __restrict__ np2_w, const float* __restrict__ src_w,
                                              const float* __restrict__ tgt_w, const float* __restrict__ inv1_w,
                                              const float* __restrict__ np1_b, const float* __restrict__ inv1_b,
                                              const float* __restrict__ z, float* __restrict__ T,
                                              float* __restrict__ c1, float* __restrict__ cz) {
    int y = blockIdx.y;
    if (y < 7) {
        int t = blockIdx.x * 256 + threadIdx.x;
        int j = t >> 7, k = t & 127;
        const float* W; int stride, off;
        switch (y) {
            case 0:  W = conv2_w; stride = 128; off = 0;   break;
            case 1:  W = np1_w;   stride = 256; off = 0;   break;
            case 2:  W = np2_w;   stride = 128; off = 0;   break;
            case 3:  W = src_w;   stride = 128; off = 0;   break;
            case 4:  W = tgt_w;   stride = 128; off = 0;   break;
            case 5:  W = inv1_w;  stride = 384; off = 0;   break;
            default: W = inv1_w;  stride = 384; off = 128; break;
        }
        T[y * 16384 + k * 128 + j] = W[j * stride + off + k];
    } else if (blockIdx.x == 0) {
        int tid = threadIdx.x;
        if (tid < 128) {
            float s = np1_b[tid];
            for (int k = 0; k < 128; k++) s += z[k] * np1_w[tid * 256 + 128 + k];
            c1[tid] = s;
        } else {
            int j = tid - 128;
            float s = inv1_b[j];
            for (int k = 0; k < 128; k++) s += z[k] * inv1_w[j * 384 + 256 + k];
            cz[j] = s;
        }
    }
}

// ---------------- generic [8192x128] @ WT[128x128] (+bias)(+relu) ----------------

__global__ __launch_bounds__(256) void k_gemm128(const float* __restrict__ A, const float* __restrict__ WT,
                                                 const float* __restrict__ bias, float* __restrict__ out,
                                                 int relu) {
    __shared__ float As[32][33];
    __shared__ float Bs[32][128];
    int tid = threadIdx.x;
    int tx = tid & 31, ty = tid >> 5;
    int row0 = blockIdx.x * 32;
    float acc[4][4] = {};
    for (int k0 = 0; k0 < 128; k0 += 32) {
        {
            int r = tid >> 3, k = (tid & 7) << 2;
            float4 v = *(const float4*)&A[(row0 + r) * HH + k0 + k];
            As[r][k] = v.x; As[r][k + 1] = v.y; As[r][k + 2] = v.z; As[r][k + 3] = v.w;
        }
#pragma unroll
        for (int i = 0; i < 4; i++) {
            int kk = (tid >> 5) + i * 8;
            int c = (tid & 31) << 2;
            *(float4*)&Bs[kk][c] = *(const float4*)&WT[(k0 + kk) * HH + c];
        }
        __syncthreads();
#pragma unroll 8
        for (int kk = 0; kk < 32; kk++) {
            float a0 = As[ty * 4 + 0][kk], a1 = As[ty * 4 + 1][kk];
            float a2 = As[ty * 4 + 2][kk], a3 = As[ty * 4 + 3][kk];
            float4 b = *(const float4*)&Bs[kk][tx * 4];
            acc[0][0] = fmaf(a0, b.x, acc[0][0]); acc[0][1] = fmaf(a0, b.y, acc[0][1]);
            acc[0][2] = fmaf(a0, b.z, acc[0][2]); acc[0][3] = fmaf(a0, b.w, acc[0][3]);
            acc[1][0] = fmaf(a1, b.x, acc[1][0]); acc[1][1] = fmaf(a1, b.y, acc[1][1]);
            acc[1][2] = fmaf(a1, b.z, acc[1][2]); acc[1][3] = fmaf(a1, b.w, acc[1][3]);
            acc[2][0] = fmaf(a2, b.x, acc[2][0]); acc[2][1] = fmaf(a2, b.y, acc[2][1]);
            acc[2][2] = fmaf(a2, b.z, acc[2][2]); acc[2][3] = fmaf(a2, b.w, acc[2][3]);
            acc[3][0] = fmaf(a3, b.x, acc[3][0]); acc[3][1] = fmaf(a3, b.y, acc[3][1]);
            acc[3][2] = fmaf(a3, b.z, acc[3][2]); acc[3][3] = fmaf(a3, b.w, acc[3][3]);
        }
        __syncthreads();
    }
#pragma unroll
    for (int i = 0; i < 4; i++) {
        float4 v = make_float4(acc[i][0], acc[i][1], acc[i][2], acc[i][3]);
        if (bias) {
            v.x += bias[tx * 4]; v.y += bias[tx * 4 + 1];
            v.z += bias[tx * 4 + 2]; v.w += bias[tx * 4 + 3];
        }
        if (relu) {
            v.x = fmaxf(v.x, 0.f); v.y = fmaxf(v.y, 0.f);
            v.z = fmaxf(v.z, 0.f); v.w = fmaxf(v.w, 0.f);
        }
        *(float4*)&out[(row0 + ty * 4 + i) * HH + tx * 4] = v;
    }
}

// ---------------- fused MLP: h2 -> t -> h3 (LDS-resident) -> Ht/Hs split-bf16 planes ----------------
// NODE-MAJOR plane layout: PP[node*384 + chunk*96 + plane*32 + colInChunk] (768 B per node).

__global__ __launch_bounds__(256) void k_mlp(const float* __restrict__ h2g, const float* __restrict__ T,
                                             const float* __restrict__ c1, const float* __restrict__ np2_b,
                                             float* __restrict__ h3g,
                                             unsigned short* __restrict__ HtP, unsigned short* __restrict__ HsP) {
    __shared__ float bufA[32][132];
    __shared__ float bufB[32][132];
    __shared__ float Bs[32][128];
    int tid = threadIdx.x;
    int tx = tid & 31, ty = tid >> 5;
    int row0 = blockIdx.x * 32;
    // load h2 tile into bufA
#pragma unroll
    for (int p = 0; p < 4; p++) {
        int q = p * 256 + tid;
        int r = q >> 5, c4 = (q & 31) * 4;
        *(float4*)&bufA[r][c4] = *(const float4*)&h2g[(size_t)(row0 + r) * HH + c4];
    }
    __syncthreads();
    for (int g = 0; g < 4; g++) {
        const float* WT;
        switch (g) {
            case 0:  WT = T + 1 * 16384; break;   // np1 (h-part)
            case 1:  WT = T + 2 * 16384; break;   // np2
            case 2:  WT = T + 4 * 16384; break;   // tgt -> Ht
            default: WT = T + 3 * 16384; break;   // src -> Hs
        }
        float (*src)[132] = (g == 1) ? bufB : bufA;
        float acc[4][4] = {};
        for (int k0 = 0; k0 < 128; k0 += 32) {
#pragma unroll
            for (int i = 0; i < 4; i++) {
                int kk = (tid >> 5) + i * 8;
                int c = (tid & 31) << 2;
                *(float4*)&Bs[kk][c] = *(const float4*)&WT[(k0 + kk) * HH + c];
            }
            __syncthreads();
#pragma unroll 8
            for (int kk = 0; kk < 32; kk++) {
                float a0 = src[ty * 4 + 0][k0 + kk], a1 = src[ty * 4 + 1][k0 + kk];
                float a2 = src[ty * 4 + 2][k0 + kk], a3 = src[ty * 4 + 3][k0 + kk];
                float4 b = *(const float4*)&Bs[kk][tx * 4];
                acc[0][0] = fmaf(a0, b.x, acc[0][0]); acc[0][1] = fmaf(a0, b.y, acc[0][1]);
                acc[0][2] = fmaf(a0, b.z, acc[0][2]); acc[0][3] = fmaf(a0, b.w, acc[0][3]);
                acc[1][0] = fmaf(a1, b.x, acc[1][0]); acc[1][1] = fmaf(a1, b.y, acc[1][1]);
                acc[1][2] = fmaf(a1, b.z, acc[1][2]); acc[1][3] = fmaf(a1, b.w, acc[1][3]);
                acc[2][0] = fmaf(a2, b.x, acc[2][0]); acc[2][1] = fmaf(a2, b.y, acc[2][1]);
                acc[2][2] = fmaf(a2, b.z, acc[2][2]); acc[2][3] = fmaf(a2, b.w, acc[2][3]);
                acc[3][0] = fmaf(a3, b.x, acc[3][0]); acc[3][1] = fmaf(a3, b.y, acc[3][1]);
                acc[3][2] = fmaf(a3, b.z, acc[3][2]); acc[3][3] = fmaf(a3, b.w, acc[3][3]);
            }
            __syncthreads();
        }
        if (g == 0) {          // t = relu(. + c1) -> bufB
#pragma unroll
            for (int i = 0; i < 4; i++)
#pragma unroll
                for (int jj = 0; jj < 4; jj++)
                    bufB[ty * 4 + i][tx * 4 + jj] = fmaxf(acc[i][jj] + c1[tx * 4 + jj], 0.f);
        } else if (g == 1) {   // h3 = . + np2_b -> bufA + global
#pragma unroll
            for (int i = 0; i < 4; i++) {
                float4 v;
                v.x = acc[i][0] + np2_b[tx * 4 + 0];
                v.y = acc[i][1] + np2_b[tx * 4 + 1];
                v.z = acc[i][2] + np2_b[tx * 4 + 2];
                v.w = acc[i][3] + np2_b[tx * 4 + 3];
                bufA[ty * 4 + i][tx * 4 + 0] = v.x; bufA[ty * 4 + i][tx * 4 + 1] = v.y;
                bufA[ty * 4 + i][tx * 4 + 2] = v.z; bufA[ty * 4 + i][tx * 4 + 3] = v.w;
                *(float4*)&h3g[(size_t)(row0 + ty * 4 + i) * HH + tx * 4] = v;
            }
        } else {               // split-bf16 3-plane emission, node-major rows
            unsigned short* PP = (g == 2) ? HtP : HsP;
            int chunk = tx >> 3;
            int cic = (tx * 4) & 31;
#pragma unroll
            for (int i = 0; i < 4; i++) {
                int row = row0 + ty * 4 + i;
                size_t off = (size_t)row * 384 + chunk * 96 + cic;
                unsigned short h[4], m[4], lo[4];
#pragma unroll
                for (int jj = 0; jj < 4; jj++) {
                    float val = acc[i][jj];
                    unsigned short hb = f2bf(val);
                    float r1 = val - bf2f(hb);
                    unsigned short mb = f2bf(r1);
                    float r2 = r1 - bf2f(mb);
                    h[jj] = hb; m[jj] = mb; lo[jj] = f2bf(r2);
                }
                *(uint2*)&PP[off] = make_uint2((unsigned)h[0] | ((unsigned)h[1] << 16),
                                               (unsigned)h[2] | ((unsigned)h[3] << 16));
                *(uint2*)&PP[off + 32] = make_uint2((unsigned)m[0] | ((unsigned)m[1] << 16),
                                                    (unsigned)m[2] | ((unsigned)m[3] << 16));
                *(uint2*)&PP[off + 64] = make_uint2((unsigned)lo[0] | ((unsigned)lo[1] << 16),
                                                    (unsigned)lo[2] | ((unsigned)lo[3] << 16));
            }
        }
    }
}

// ---------------- candidate counts + valid flags ----------------

__global__ __launch_bounds__(256) void k_cnt_valid(const int* __restrict__ depth, const float* __restrict__ x,
                                                   int* __restrict__ cnt, float* __restrict__ out) {
    int v = blockIdx.x * 256 + threadIdx.x;
    if (v >= NN) return;
    int limit = depth[v] + 1;   // depth[v]-1+DEPTH_PERTURB
    int lo = 0, hi = NN;
    while (lo < hi) { int mid = (lo + hi) >> 1; if (depth[mid] <= limit) lo = mid + 1; else hi = mid; }
    cnt[v] = lo;
    int type = (int)(x[v * 2] + 0.5f);
    bool tv = (depth[v] >= 1) && (type != 0);
    out[4 * NN * 2 + v * 2 + 0] = (tv && lo >= 1) ? 1.0f : 0.0f;
    out[4 * NN * 2 + v * 2 + 1] = (tv && type == 2 && lo >= 2) ? 1.0f : 0.0f;
}

// ---------------- active tile list (128-row v-blocks -> 64 entries, one wave) ----------------

__global__ __launch_bounds__(64) void k_tiles(const int* __restrict__ cnt, int* __restrict__ nact,
                                              int* __restrict__ tlist, int* __restrict__ ntiles) {
    int lane = threadIdx.x;   // 0..63, one per 128-row v-block
    int cmax = cnt[lane * VT + VT - 1];
    int n = (cmax + SEG - 1) / SEG;   // <= 64
    nact[lane] = n;
    int x = n;
    for (int off = 1; off < 64; off <<= 1) {
        int y = __shfl_up(x, off, 64);
        if (lane >= off) x += y;
    }
    int base = x - n;
    for (int s = 0; s < n; s++) tlist[base + s] = (lane << 8) | s;
    if (lane == 63) *ntiles = x;
}

// ---------------- fused masked GEMM + top-2 (stage 1, LDS-staged B, split-bf16 MFMA) ----------------
// Persistent blocks; 4 waves/block, each holds TWO 16-row A-sets (registers). B tile staged
// into LDS once per block in 64-u chunks (784 B padded rows -> balanced ds_read_b128 banks);
// all 4 waves consume from LDS. Node-major 768 B rows -> one base + imm offsets per u-step.

__global__ __launch_bounds__(256, 2) void k_top2_stage1(
    const unsigned short* __restrict__ HtP, const unsigned short* __restrict__ HsP,
    const int* __restrict__ cnt, const int* __restrict__ tlist,
    const int* __restrict__ ntiles, int* __restrict__ tctr,
    float* __restrict__ pval, int* __restrict__ pidx) {
    __shared__ unsigned short Bsh[64 * 392];   // 64 u-rows x 784 B (768 + 16 pad)
    __shared__ int tsh;
    int tid = threadIdx.x;
    int wave = tid >> 6, lane = tid & 63;
    int l = lane & 15, quad = lane >> 4;
    int nt = *ntiles;
    for (;;) {
        __syncthreads();   // protect Bsh + tsh across tiles
        if (tid == 0) tsh = atomicAdd(tctr, 1);
        __syncthreads();
        int t = tsh;
        if (t >= nt) return;
        int code = tlist[t];
        int v0 = (code >> 8) * VT;
        int seg = code & 255;
        int ub0 = seg * SEG;
        int vbase = v0 + wave * 32;
        // A fragments: [set][chunk][hi|mid|lo]; node-major rows, one base + imm offsets
        bf16x8 afr[2][4][3];
#pragma unroll
        for (int s = 0; s < 2; s++) {
            const unsigned short* ap = &HtP[(size_t)(vbase + s * 16 + l) * 384 + quad * 8];
#pragma unroll
            for (int c = 0; c < 4; c++) {
                afr[s][c][0] = *(const bf16x8*)&ap[c * 96];
                afr[s][c][1] = *(const bf16x8*)&ap[c * 96 + 32];
                afr[s][c][2] = *(const bf16x8*)&ap[c * 96 + 64];
            }
        }
        // C/D layout (16x16x32): col(u)=lane&15, row(v)=quad*4+reg (per set)
        int creg[8];
#pragma unroll
        for (int i = 0; i < 8; i++)
            creg[i] = cnt[vbase + (i >> 2) * 16 + quad * 4 + (i & 3)];
        float t1v[8], t2v[8]; int t1i[8], t2i[8];
#pragma unroll
        for (int i = 0; i < 8; i++) { t1v[i] = NEGV; t2v[i] = NEGV; t1i[i] = 0x7fffffff; t2i[i] = 0x7fffffff; }
        int cmax = cnt[v0 + VT - 1];
        int uend = ub0 + SEG; if (uend > cmax) uend = cmax;
        for (int cb = ub0; cb < uend; cb += 64) {
            // stage 64-u chunk of B: straight row copy (768 B rows, 16 B pad per LDS row)
            __syncthreads();
#pragma unroll
            for (int gi = 0; gi < 12; gi++) {
                int g = gi * 256 + tid;            // 0..3071
                int r = g / 48, w = g - r * 48;
                *(uint4*)&Bsh[r * 392 + w * 8] = *(const uint4*)&HsP[(size_t)(cb + r) * 384 + w * 8];
            }
            __syncthreads();
            int cend = cb + 64; if (cend > uend) cend = uend;
            for (int u0 = cb; u0 < cend; u0 += 16) {
                int u = u0 + l;
                const unsigned short* bp = &Bsh[(u0 - cb + l) * 392 + quad * 8];
                f32x4 acc0 = {0.f, 0.f, 0.f, 0.f}, acc1 = {0.f, 0.f, 0.f, 0.f};
#pragma unroll
                for (int c = 0; c < 4; c++) {
                    bf16x8 bh = *(const bf16x8*)&bp[c * 96];
                    bf16x8 bm = *(const bf16x8*)&bp[c * 96 + 32];
                    bf16x8 bl = *(const bf16x8*)&bp[c * 96 + 64];
                    acc0 = __builtin_amdgcn_mfma_f32_16x16x32_bf16(afr[0][c][0], bh, acc0, 0, 0, 0);
                    acc1 = __builtin_amdgcn_mfma_f32_16x16x32_bf16(afr[1][c][0], bh, acc1, 0, 0, 0);
                    acc0 = __builtin_amdgcn_mfma_f32_16x16x32_bf16(afr[0][c][0], bm, acc0, 0, 0, 0);
                    acc1 = __builtin_amdgcn_mfma_f32_16x16x32_bf16(afr[1][c][0], bm, acc1, 0, 0, 0);
                    acc0 = __builtin_amdgcn_mfma_f32_16x16x32_bf16(afr[0][c][1], bh, acc0, 0, 0, 0);
                    acc1 = __builtin_amdgcn_mfma_f32_16x16x32_bf16(afr[1][c][1], bh, acc1, 0, 0, 0);
                    acc0 = __builtin_amdgcn_mfma_f32_16x16x32_bf16(afr[0][c][0], bl, acc0, 0, 0, 0);
                    acc1 = __builtin_amdgcn_mfma_f32_16x16x32_bf16(afr[1][c][0], bl, acc1, 0, 0, 0);
                    acc0 = __builtin_amdgcn_mfma_f32_16x16x32_bf16(afr[0][c][2], bh, acc0, 0, 0, 0);
                    acc1 = __builtin_amdgcn_mfma_f32_16x16x32_bf16(afr[1][c][2], bh, acc1, 0, 0, 0);
                    acc0 = __builtin_amdgcn_mfma_f32_16x16x32_bf16(afr[0][c][1], bm, acc0, 0, 0, 0);
                    acc1 = __builtin_amdgcn_mfma_f32_16x16x32_bf16(afr[1][c][1], bm, acc1, 0, 0, 0);
                }
#pragma unroll
                for (int i = 0; i < 8; i++) {
                    float sv = (i < 4) ? acc0[i & 3] : acc1[i & 3];
                    float val = (u < creg[i]) ? sv : NEGV;   // masked: NEG with real index
                    if (val > t1v[i] || (val == t1v[i] && u < t1i[i])) {
                        t2v[i] = t1v[i]; t2i[i] = t1i[i]; t1v[i] = val; t1i[i] = u;
                    } else if (val > t2v[i] || (val == t2v[i] && u < t2i[i])) {
                        t2v[i] = val; t2i[i] = u;
                    }
                }
            }
        }
        // merge top-2 across the 16 lanes of each quad group (disjoint u sets)
#pragma unroll
        for (int m = 1; m <= 8; m <<= 1) {
#pragma unroll
            for (int i = 0; i < 8; i++) {
                float ov1 = __shfl_xor(t1v[i], m, 64);
                int   oi1 = __shfl_xor(t1i[i], m, 64);
                float ov2 = __shfl_xor(t2v[i], m, 64);
                int   oi2 = __shfl_xor(t2i[i], m, 64);
                bool b1 = (ov1 > t1v[i]) || (ov1 == t1v[i] && oi1 < t1i[i]);
                float w1v = b1 ? ov1 : t1v[i]; int w1i = b1 ? oi1 : t1i[i];
                float l1v = b1 ? t1v[i] : ov1; int l1i = b1 ? t1i[i] : oi1;
                float c2v = b1 ? ov2 : t2v[i]; int c2i = b1 ? oi2 : t2i[i];
                bool b2 = (l1v > c2v) || (l1v == c2v && l1i < c2i);
                t1v[i] = w1v; t1i[i] = w1i;
                t2v[i] = b2 ? l1v : c2v; t2i[i] = b2 ? l1i : c2i;
            }
        }
        if (l == 0) {
#pragma unroll
            for (int i = 0; i < 8; i++) {
                int v = vbase + (i >> 2) * 16 + quad * 4 + (i & 3);
                int o = (v * NSEG + seg) * 2;
                pval[o] = t1v[i];     pidx[o] = t1i[i];
                pval[o + 1] = t2v[i]; pidx[o + 1] = t2i[i];
            }
        }
    }
}

// ---------------- fused merge + inversion epilogue: one wave per v ----------------

__global__ __launch_bounds__(256) void k_merge_inv(const float* __restrict__ pval, const int* __restrict__ pidx,
                                                   const int* __restrict__ nact,
                                                   const float* __restrict__ P, const float* __restrict__ Q,
                                                   const float* __restrict__ cz, const float* __restrict__ w2,
                                                   const float* __restrict__ b2, float* __restrict__ out) {
    int gid = blockIdx.x * 256 + threadIdx.x;
    int v = gid >> 6, lane = gid & 63;
    if (v >= NN) return;
    int na = nact[v >> 7];
    float v1 = NEGV, v2 = NEGV; int i1 = 0x7fffffff, i2 = 0x7fffffff;
    if (lane < na) {
        int o = (v * NSEG + lane) * 2;
        v1 = pval[o];     i1 = pidx[o];
        v2 = pval[o + 1]; i2 = pidx[o + 1];
    }
#pragma unroll
    for (int m = 1; m <= 32; m <<= 1) {
        float ov1 = __shfl_xor(v1, m, 64);
        int   oi1 = __shfl_xor(i1, m, 64);
        float ov2 = __shfl_xor(v2, m, 64);
        int   oi2 = __shfl_xor(i2, m, 64);
        bool b1 = (ov1 > v1) || (ov1 == v1 && oi1 < i1);
        float w1v = b1 ? ov1 : v1; int w1i = b1 ? oi1 : i1;
        float l1v = b1 ? v1 : ov1; int l1i = b1 ? i1 : oi1;
        float c2v = b1 ? ov2 : v2; int c2i = b1 ? oi2 : i2;
        bool b2 = (l1v > c2v) || (l1v == c2v && l1i < c2i);
        v1 = w1v; i1 = w1i;
        v2 = b2 ? l1v : c2v; i2 = b2 ? l1i : c2i;
    }
    if (na == 0) { v1 = NEGV; v2 = NEGV; i1 = 0; i2 = 1; }
    int u1 = i1, u2 = i2;   // always in [0, NN) by construction
    float cza = cz[lane], czb = cz[64 + lane];
    float w2a = w2[lane], w2b = w2[64 + lane];
    float Qa = Q[(size_t)v * HH + lane], Qb = Q[(size_t)v * HH + 64 + lane];
    float p0 = fmaxf(P[(size_t)u1 * HH + lane] + Qa + cza, 0.f) * w2a +
               fmaxf(P[(size_t)u1 * HH + 64 + lane] + Qb + czb, 0.f) * w2b;
    float p1 = fmaxf(P[(size_t)u2 * HH + lane] + Qa + cza, 0.f) * w2a +
               fmaxf(P[(size_t)u2 * HH + 64 + lane] + Qb + czb, 0.f) * w2b;
#pragma unroll
    for (int off = 32; off >= 1; off >>= 1) {
        p0 += __shfl_down(p0, off, 64);
        p1 += __shfl_down(p1, off, 64);
    }
    if (lane == 0) {
        float bb = b2[0];
        float l0 = p0 + bb, l1 = p1 + bb;
        out[v * 2 + 0] = v1; out[v * 2 + 1] = v2;                 // top_vals
        out[NN * 2 + v * 2 + 0] = l0;                             // inv_logit
        out[NN * 2 + v * 2 + 1] = l1;
        out[2 * NN * 2 + v * 2 + 0] = (float)i1;                  // top_idx
        out[2 * NN * 2 + v * 2 + 1] = (float)i2;
        out[3 * NN * 2 + v * 2 + 0] = (l0 > 0.f) ? 1.f : 0.f;     // inv_bit
        out[3 * NN * 2 + v * 2 + 1] = (l1 > 0.f) ? 1.f : 0.f;
    }
}

// ---------------- launch ----------------

extern "C" void kernel_launch(void* const* d_in, const int* in_sizes, int n_in,
                              void* d_out, int out_size, void* d_ws, size_t ws_size,
                              hipStream_t stream) {
    const float* x       = (const float*)d_in[0];
    const float* z       = (const float*)d_in[1];
    const int*   eidx    = (const int*)d_in[2];
    const int*   depth   = (const int*)d_in[3];
    const float* conv1_w = (const float*)d_in[4];
    const float* conv1_b = (const float*)d_in[5];
    const float* conv2_w = (const float*)d_in[6];
    const float* conv2_b = (const float*)d_in[7];
    const float* np1_w   = (const float*)d_in[8];
    const float* np1_b   = (const float*)d_in[9];
    const float* np2_w   = (const float*)d_in[10];
    const float* np2_b   = (const float*)d_in[11];
    const float* src_w   = (const float*)d_in[12];
    const float* tgt_w   = (const float*)d_in[13];
    const float* inv1_w  = (const float*)d_in[14];
    const float* inv1_b  = (const float*)d_in[15];
    const float* inv2_w  = (const float*)d_in[16];
    const float* inv2_b  = (const float*)d_in[17];
    float* out = (float*)d_out;
    float* wsf = (float*)d_ws;

    const int NH = NN * HH;   // 1,048,576 floats = 4 MB
    float* R0 = wsf;                          // h1/h2/h3
    float* R1 = wsf + (size_t)NH;             // xw2 / planes / P
    unsigned short* HtP = (unsigned short*)R1;
    unsigned short* HsP = HtP + 3 * (size_t)NH;
    float* P = wsf + (size_t)NH;
    float* Q = wsf + 2 * (size_t)NH;
    float* pval = wsf + 4 * (size_t)NH;
    int*   pidx = (int*)(wsf + 5 * (size_t)NH);
    float* T  = wsf + 6 * (size_t)NH;
    float* c1 = T + 7 * 16384;
    float* cz = c1 + 128;
    float* rsq  = cz + 128;
    float* dinv = rsq + NN;
    int* degi   = (int*)(dinv + NN);
    int* rowptr = degi + NN;             // NN+1
    int* cursor = rowptr + NN + 1;
    int* cnt    = cursor + NN;
    int* nact   = cnt + NN;              // 64
    int* ntiles = nact + 64;
    int* tctr   = ntiles + 1;
    int* tlist  = tctr + 1;              // <= 4096
    int* ecsr   = tlist + 4096;          // EE

    const int* esrc = eidx;
    const int* edst = eidx + EE;

    hipMemsetAsync(degi, 0, NN * sizeof(int), stream);
    hipMemsetAsync(cursor, 0, NN * sizeof(int), stream);
    hipMemsetAsync(tctr, 0, sizeof(int), stream);
    k_prep<<<dim3(64, 8), 256, 0, stream>>>(conv2_w, np1_w, np2_w, src_w, tgt_w, inv1_w,
                                            np1_b, inv1_b, z, T, c1, cz);
    k_deg<<<EE / 256, 256, 0, stream>>>(edst, degi);
    k_scan<<<1, 1024, 0, stream>>>(degi, rowptr, dinv, rsq);
    k_fill<<<EE / 256, 256, 0, stream>>>(esrc, edst, rowptr, cursor, ecsr);
    k_gather1<<<NN * 64 / 256, 256, 0, stream>>>(rowptr, ecsr, rsq, dinv, x, conv1_w, conv1_b, R0);  // h1
    k_gemm128<<<256, 256, 0, stream>>>(R0, T + 0 * 16384, nullptr, R1, 0);                           // xw2
    k_gather2<<<NN * 64 / 256, 256, 0, stream>>>(rowptr, ecsr, rsq, dinv, R1, conv2_b, R0);          // h2
    k_mlp<<<256, 256, 0, stream>>>(R0, T, c1, np2_b, R0, HtP, HsP);        // h3 (in-place) + planes
    k_cnt_valid<<<NN / 256, 256, 0, stream>>>(depth, x, cnt, out);
    k_tiles<<<1, 64, 0, stream>>>(cnt, nact, tlist, ntiles);
    k_top2_stage1<<<768, 256, 0, stream>>>(HtP, HsP, cnt, tlist, ntiles, tctr, pval, pidx);
    k_gemm128<<<256, 256, 0, stream>>>(R0, T + 5 * 16384, nullptr, P, 0);  // P = h3@inv1a^T
    k_gemm128<<<256, 256, 0, stream>>>(R0, T + 6 * 16384, nullptr, Q, 0);  // Q = h3@inv1b^T
    k_merge_inv<<<NN / 4, 256, 0, stream>>>(pval, pidx, nact, P, Q, cz, inv2_w, inv2_b, out);
}